// Round 1
// baseline (834.390 us; speedup 1.0000x reference)
//
#include <hip/hip_runtime.h>
#include <hip/hip_bf16.h>

#define DIMN 128
#define LN_EPS 1e-5f

typedef __bf16 bf16x8 __attribute__((ext_vector_type(8)));
typedef float f32x4 __attribute__((ext_vector_type(4)));

// ---------------- W split (f32 -> bf16 hi + bf16 lo) ----------------
__global__ void k_wsplit(const float* __restrict__ Wq, const float* __restrict__ Wk,
                         const float* __restrict__ Wv, const float* __restrict__ Wp,
                         __bf16* __restrict__ wsplit) {
    const float* W = (blockIdx.y == 0) ? Wq : (blockIdx.y == 1) ? Wk
                   : (blockIdx.y == 2) ? Wv : Wp;
    __bf16* hi = wsplit + (size_t)blockIdx.y * 32768;
    __bf16* lo = hi + 16384;
    int i = blockIdx.x * 256 + threadIdx.x;
    float x = W[i];
    __bf16 h = (__bf16)x;
    hi[i] = h;
    lo[i] = (__bf16)(x - (float)h);
}

// ---------------- projection GEMM: Out[M,128] = X @ W^T + b ----------------
// 3-term bf16 split MFMA (16x16x32). Block = 4 waves, 64 rows/block (16/wave).
__global__ __launch_bounds__(256) void k_proj(const float* __restrict__ X,
        const __bf16* __restrict__ wh, const __bf16* __restrict__ wl,
        const float* __restrict__ bias, float* __restrict__ Out, int M) {
    int lane = threadIdx.x & 63;
    int wid  = threadIdx.x >> 6;
    int r = lane & 15, g = lane >> 4;
    int rb = blockIdx.x * 64 + wid * 16;

    int arow = rb + r; if (arow >= M) arow = M - 1;
    const float* xrow = X + (size_t)arow * DIMN;
    bf16x8 Ah[4], Al[4];
#pragma unroll
    for (int ks = 0; ks < 4; ++ks) {
        const float* px = xrow + ks * 32 + g * 8;
#pragma unroll
        for (int i = 0; i < 8; ++i) {
            float v = px[i];
            __bf16 h = (__bf16)v;
            Ah[ks][i] = h;
            Al[ks][i] = (__bf16)(v - (float)h);
        }
    }
#pragma unroll
    for (int ct = 0; ct < 8; ++ct) {
        f32x4 acc = {0.f, 0.f, 0.f, 0.f};
        int n = ct * 16 + r;
        const __bf16* bh = wh + n * DIMN + g * 8;
        const __bf16* bl = wl + n * DIMN + g * 8;
#pragma unroll
        for (int ks = 0; ks < 4; ++ks) {
            bf16x8 Bh = *(const bf16x8*)(bh + ks * 32);
            bf16x8 Bl = *(const bf16x8*)(bl + ks * 32);
            acc = __builtin_amdgcn_mfma_f32_16x16x32_bf16(Ah[ks], Bh, acc, 0, 0, 0);
            acc = __builtin_amdgcn_mfma_f32_16x16x32_bf16(Ah[ks], Bl, acc, 0, 0, 0);
            acc = __builtin_amdgcn_mfma_f32_16x16x32_bf16(Al[ks], Bh, acc, 0, 0, 0);
        }
        float bn = bias[n];
#pragma unroll
        for (int i = 0; i < 4; ++i) {
            int row = rb + g * 4 + i;
            if (row < M) Out[(size_t)row * DIMN + n] = acc[i] + bn;
        }
    }
}

// ---------------- CSR build ----------------
__global__ void k_hist(const int* __restrict__ qidx, int* __restrict__ counts, int E) {
    int i = blockIdx.x * 256 + threadIdx.x;
    if (i < E) atomicAdd(&counts[qidx[i]], 1);
}

__global__ __launch_bounds__(1024) void k_scan(const int* __restrict__ counts,
                                               int* __restrict__ offs, int n) {
    __shared__ int sums[1024];
    int t = threadIdx.x;
    int chunk = (n + 1023) >> 10;
    int b0 = t * chunk;
    int b1 = b0 + chunk; if (b1 > n) b1 = n;
    int s = 0;
    for (int i = b0; i < b1; ++i) s += counts[i];
    sums[t] = s;
    __syncthreads();
    for (int off = 1; off < 1024; off <<= 1) {
        int v = (t >= off) ? sums[t - off] : 0;
        __syncthreads();
        sums[t] += v;
        __syncthreads();
    }
    int run = (t == 0) ? 0 : sums[t - 1];
    for (int i = b0; i < b1; ++i) { offs[i] = run; run += counts[i]; }
    if (t == 1023) offs[n] = sums[1023];
}

__global__ void k_scatter(const int* __restrict__ qidx, const int* __restrict__ kidx,
                          const int* __restrict__ offs, int* __restrict__ cursor,
                          int* __restrict__ skey, int E) {
    int i = blockIdx.x * 256 + threadIdx.x;
    if (i < E) {
        int q = qidx[i];
        int pos = offs[q] + atomicAdd(&cursor[q], 1);
        skey[pos] = kidx[i];
    }
}

// ---------------- per-query online-softmax aggregation (1 wave / query) ----------------
__global__ __launch_bounds__(256) void k_attn(
        const float* __restrict__ Qp, const float* __restrict__ Kp,
        const float* __restrict__ Vp, const int* __restrict__ offs,
        const int* __restrict__ skey, const float* __restrict__ a,
        const float* __restrict__ prelu_w, float* __restrict__ msg, int NQ_) {
    int lane = threadIdx.x & 63;
    int q = blockIdx.x * 4 + (threadIdx.x >> 6);
    if (q >= NQ_) return;
    int d = lane * 2;
    float a0 = a[d], a1 = a[d + 1];
    float pw = prelu_w[0];
    float q0 = Qp[(size_t)q * DIMN + d], q1 = Qp[(size_t)q * DIMN + d + 1];
    int beg = offs[q], end = offs[q + 1];
    float m = -3.4e38f, den = 0.f, acc0 = 0.f, acc1 = 0.f;
    for (int j = beg; j < end; ++j) {
        int k = skey[j];
        const float* kr = Kp + (size_t)k * DIMN + d;
        float s0 = q0 + kr[0], s1 = q1 + kr[1];
        s0 = s0 >= 0.f ? s0 : pw * s0;
        s1 = s1 >= 0.f ? s1 : pw * s1;
        float e = a0 * s0 + a1 * s1;
        e += __shfl_xor(e, 1, 64);   // reduce over the 8 lanes of this head
        e += __shfl_xor(e, 2, 64);
        e += __shfl_xor(e, 4, 64);
        const float* vr = Vp + (size_t)k * DIMN + d;
        float v0 = vr[0], v1 = vr[1];
        float mn = fmaxf(m, e);
        float sc = __expf(m - mn);
        float w  = __expf(e - mn);
        den  = den  * sc + w;
        acc0 = acc0 * sc + w * v0;
        acc1 = acc1 * sc + w * v1;
        m = mn;
    }
    float inv = den > 0.f ? 1.f / den : 0.f;
    msg[(size_t)q * DIMN + d]     = acc0 * inv;   // msg aliases Qp (row q only)
    msg[(size_t)q * DIMN + d + 1] = acc1 * inv;
}

// ---------------- final: x = query + msg@Wp^T + bp; LayerNorm; write out ----------------
__global__ __launch_bounds__(256) void k_final(
        const float* __restrict__ msg, const __bf16* __restrict__ wh,
        const __bf16* __restrict__ wl, const float* __restrict__ bp,
        const float* __restrict__ query, const float* __restrict__ lng,
        const float* __restrict__ lnb, float* __restrict__ out, int M) {
    int lane = threadIdx.x & 63;
    int wid  = threadIdx.x >> 6;
    int r = lane & 15, g = lane >> 4;
    int rb = blockIdx.x * 64 + wid * 16;

    int arow = rb + r; if (arow >= M) arow = M - 1;
    const float* xrow = msg + (size_t)arow * DIMN;
    bf16x8 Ah[4], Al[4];
#pragma unroll
    for (int ks = 0; ks < 4; ++ks) {
        const float* px = xrow + ks * 32 + g * 8;
#pragma unroll
        for (int i = 0; i < 8; ++i) {
            float v = px[i];
            __bf16 h = (__bf16)v;
            Ah[ks][i] = h;
            Al[ks][i] = (__bf16)(v - (float)h);
        }
    }
    float xv[8][4];
#pragma unroll
    for (int ct = 0; ct < 8; ++ct) {
        f32x4 acc = {0.f, 0.f, 0.f, 0.f};
        int n = ct * 16 + r;
        const __bf16* bh = wh + n * DIMN + g * 8;
        const __bf16* bl = wl + n * DIMN + g * 8;
#pragma unroll
        for (int ks = 0; ks < 4; ++ks) {
            bf16x8 Bh = *(const bf16x8*)(bh + ks * 32);
            bf16x8 Bl = *(const bf16x8*)(bl + ks * 32);
            acc = __builtin_amdgcn_mfma_f32_16x16x32_bf16(Ah[ks], Bh, acc, 0, 0, 0);
            acc = __builtin_amdgcn_mfma_f32_16x16x32_bf16(Ah[ks], Bl, acc, 0, 0, 0);
            acc = __builtin_amdgcn_mfma_f32_16x16x32_bf16(Al[ks], Bh, acc, 0, 0, 0);
        }
        float bn = bp[n];
#pragma unroll
        for (int i = 0; i < 4; ++i) {
            int row = rb + g * 4 + i;
            int rc = row < M ? row : M - 1;
            xv[ct][i] = acc[i] + bn + query[(size_t)rc * DIMN + n];
        }
    }
#pragma unroll
    for (int i = 0; i < 4; ++i) {
        float s = 0.f, ss = 0.f;
#pragma unroll
        for (int ct = 0; ct < 8; ++ct) { s += xv[ct][i]; ss += xv[ct][i] * xv[ct][i]; }
        s += __shfl_xor(s, 1, 64);  ss += __shfl_xor(ss, 1, 64);
        s += __shfl_xor(s, 2, 64);  ss += __shfl_xor(ss, 2, 64);
        s += __shfl_xor(s, 4, 64);  ss += __shfl_xor(ss, 4, 64);
        s += __shfl_xor(s, 8, 64);  ss += __shfl_xor(ss, 8, 64);
        float mean = s * (1.f / DIMN);
        float var  = ss * (1.f / DIMN) - mean * mean;
        float rstd = rsqrtf(var + LN_EPS);
        int row = rb + g * 4 + i;
#pragma unroll
        for (int ct = 0; ct < 8; ++ct) {
            int n = ct * 16 + r;
            if (row < M)
                out[(size_t)row * DIMN + n] = (xv[ct][i] - mean) * rstd * lng[n] + lnb[n];
        }
    }
}

extern "C" void kernel_launch(void* const* d_in, const int* in_sizes, int n_in,
                              void* d_out, int out_size, void* d_ws, size_t ws_size,
                              hipStream_t stream) {
    const float* query = (const float*)d_in[0];
    const float* keys  = (const float*)d_in[1];
    const float* values= (const float*)d_in[2];
    const int*   qidx  = (const int*)d_in[3];
    const int*   kidx  = (const int*)d_in[4];
    const float* Wq    = (const float*)d_in[5];
    const float* bq    = (const float*)d_in[6];
    const float* Wk    = (const float*)d_in[7];
    const float* bk    = (const float*)d_in[8];
    const float* Wv    = (const float*)d_in[9];
    const float* bv    = (const float*)d_in[10];
    const float* Wp    = (const float*)d_in[11];
    const float* bp    = (const float*)d_in[12];
    const float* a     = (const float*)d_in[13];
    const float* pw    = (const float*)d_in[14];
    const float* lng   = (const float*)d_in[15];
    const float* lnb   = (const float*)d_in[16];

    int NQ_ = in_sizes[0] / DIMN;
    int NK_ = in_sizes[1] / DIMN;
    int E_  = in_sizes[3];

    char* p = (char*)d_ws;
    __bf16* wsplit = (__bf16*)p;
    size_t off = (size_t)4 * 32768 * sizeof(__bf16);
    float* Qp = (float*)(p + off); off += (size_t)NQ_ * DIMN * 4;
    float* Kp = (float*)(p + off); off += (size_t)NK_ * DIMN * 4;
    float* Vp = (float*)(p + off); off += (size_t)NK_ * DIMN * 4;
    int* counts = (int*)(p + off); off += (((size_t)NQ_ * 4) + 127) / 128 * 128;
    int* cursor = (int*)(p + off); off += (((size_t)NQ_ * 4) + 127) / 128 * 128;
    int* offs   = (int*)(p + off); off += (((size_t)(NQ_ + 1) * 4) + 127) / 128 * 128;
    int* skey   = (int*)(p + off); off += (size_t)E_ * 4;
    float* msg  = Qp;  // aliasing is safe: wave for query q reads only Qp row q

    hipMemsetAsync(counts, 0, (size_t)NQ_ * 4, stream);
    hipMemsetAsync(cursor, 0, (size_t)NQ_ * 4, stream);

    k_wsplit<<<dim3(64, 4), 256, 0, stream>>>(Wq, Wk, Wv, Wp, wsplit);

    int gm = (NQ_ + 63) / 64;
    int gk = (NK_ + 63) / 64;
    k_proj<<<gm, 256, 0, stream>>>(query,  wsplit + 0 * 32768, wsplit + 0 * 32768 + 16384, bq, Qp, NQ_);
    k_proj<<<gk, 256, 0, stream>>>(keys,   wsplit + 1 * 32768, wsplit + 1 * 32768 + 16384, bk, Kp, NK_);
    k_proj<<<gk, 256, 0, stream>>>(values, wsplit + 2 * 32768, wsplit + 2 * 32768 + 16384, bv, Vp, NK_);

    int ge = (E_ + 255) / 256;
    k_hist<<<ge, 256, 0, stream>>>(qidx, counts, E_);
    k_scan<<<1, 1024, 0, stream>>>(counts, offs, NQ_);
    k_scatter<<<ge, 256, 0, stream>>>(qidx, kidx, offs, cursor, skey, E_);

    k_attn<<<(NQ_ + 3) / 4, 256, 0, stream>>>(Qp, Kp, Vp, offs, skey, a, pw, msg, NQ_);

    k_final<<<gm, 256, 0, stream>>>(msg, wsplit + 3 * 32768, wsplit + 3 * 32768 + 16384,
                                    bp, query, lng, lnb, (float*)d_out, NQ_);
}

// Round 2
// 553.454 us; speedup vs baseline: 1.5076x; 1.5076x over previous
//
#include <hip/hip_runtime.h>
#include <hip/hip_bf16.h>

#define DIMN 128
#define LN_EPS 1e-5f

typedef __bf16 bf16x8 __attribute__((ext_vector_type(8)));
typedef float f32x4 __attribute__((ext_vector_type(4)));

__device__ __forceinline__ float bf_even(uint32_t u) {  // element at even dim (low 16 bits)
    union { uint32_t u; float f; } c; c.u = u << 16; return c.f;
}
__device__ __forceinline__ float bf_odd(uint32_t u) {   // element at odd dim (high 16 bits)
    union { uint32_t u; float f; } c; c.u = u & 0xffff0000u; return c.f;
}

// ---------------- W split (f32 -> bf16 hi + bf16 lo) ----------------
__global__ void k_wsplit(const float* __restrict__ Wq, const float* __restrict__ Wk,
                         const float* __restrict__ Wv, const float* __restrict__ Wp,
                         __bf16* __restrict__ wsplit) {
    const float* W = (blockIdx.y == 0) ? Wq : (blockIdx.y == 1) ? Wk
                   : (blockIdx.y == 2) ? Wv : Wp;
    __bf16* hi = wsplit + (size_t)blockIdx.y * 32768;
    __bf16* lo = hi + 16384;
    int i = blockIdx.x * 256 + threadIdx.x;
    float x = W[i];
    __bf16 h = (__bf16)x;
    hi[i] = h;
    lo[i] = (__bf16)(x - (float)h);
}

// ---------------- projection GEMM: Out[M,128] = X @ W^T + b ----------------
// 3-term bf16 split MFMA (16x16x32). Block = 4 waves, 64 rows/block (16/wave).
// OT = float (Qp) or __bf16 (KV halves); ostride/ocol place K and V halves.
template <typename OT>
__global__ __launch_bounds__(256) void k_proj(const float* __restrict__ X,
        const __bf16* __restrict__ wh, const __bf16* __restrict__ wl,
        const float* __restrict__ bias, OT* __restrict__ Out, int M,
        int ostride, int ocol) {
    int lane = threadIdx.x & 63;
    int wid  = threadIdx.x >> 6;
    int r = lane & 15, g = lane >> 4;
    int rb = blockIdx.x * 64 + wid * 16;

    int arow = rb + r; if (arow >= M) arow = M - 1;
    const float* xrow = X + (size_t)arow * DIMN;
    bf16x8 Ah[4], Al[4];
#pragma unroll
    for (int ks = 0; ks < 4; ++ks) {
        const float* px = xrow + ks * 32 + g * 8;
#pragma unroll
        for (int i = 0; i < 8; ++i) {
            float v = px[i];
            __bf16 h = (__bf16)v;
            Ah[ks][i] = h;
            Al[ks][i] = (__bf16)(v - (float)h);
        }
    }
#pragma unroll
    for (int ct = 0; ct < 8; ++ct) {
        f32x4 acc = {0.f, 0.f, 0.f, 0.f};
        int n = ct * 16 + r;
        const __bf16* bh = wh + n * DIMN + g * 8;
        const __bf16* bl = wl + n * DIMN + g * 8;
#pragma unroll
        for (int ks = 0; ks < 4; ++ks) {
            bf16x8 Bh = *(const bf16x8*)(bh + ks * 32);
            bf16x8 Bl = *(const bf16x8*)(bl + ks * 32);
            acc = __builtin_amdgcn_mfma_f32_16x16x32_bf16(Ah[ks], Bh, acc, 0, 0, 0);
            acc = __builtin_amdgcn_mfma_f32_16x16x32_bf16(Ah[ks], Bl, acc, 0, 0, 0);
            acc = __builtin_amdgcn_mfma_f32_16x16x32_bf16(Al[ks], Bh, acc, 0, 0, 0);
        }
        float bn = bias[n];
#pragma unroll
        for (int i = 0; i < 4; ++i) {
            int row = rb + g * 4 + i;
            if (row < M) Out[(size_t)row * ostride + ocol + n] = (OT)(acc[i] + bn);
        }
    }
}

// ---------------- CSR build ----------------
__global__ void k_hist(const int* __restrict__ qidx, int* __restrict__ counts, int E) {
    int i = blockIdx.x * 256 + threadIdx.x;
    if (i < E) atomicAdd(&counts[qidx[i]], 1);
}

// two-level scan: scan1 (per-block exclusive + block sums), scan2 (scan block
// sums, single block), scan3 (add back + write total)
__global__ __launch_bounds__(256) void k_scan1(const int* __restrict__ counts,
        int* __restrict__ offs, int* __restrict__ bsum, int n) {
    __shared__ int s[256];
    int t = threadIdx.x;
    int i = blockIdx.x * 256 + t;
    int v = (i < n) ? counts[i] : 0;
    s[t] = v;
    __syncthreads();
    for (int o = 1; o < 256; o <<= 1) {
        int x = (t >= o) ? s[t - o] : 0;
        __syncthreads();
        s[t] += x;
        __syncthreads();
    }
    if (i < n) offs[i] = s[t] - v;       // exclusive within block
    if (t == 255) bsum[blockIdx.x] = s[t];
}

__global__ __launch_bounds__(1024) void k_scan2(int* __restrict__ bsum, int nb) {
    __shared__ int s[1024];
    int t = threadIdx.x;
    int v = (t < nb) ? bsum[t] : 0;
    s[t] = v;
    __syncthreads();
    for (int o = 1; o < 1024; o <<= 1) {
        int x = (t >= o) ? s[t - o] : 0;
        __syncthreads();
        s[t] += x;
        __syncthreads();
    }
    if (t < nb) bsum[t] = s[t];          // inclusive
}

__global__ __launch_bounds__(256) void k_scan3(int* __restrict__ offs,
        const int* __restrict__ bsum, int n, int nb) {
    int i = blockIdx.x * 256 + threadIdx.x;
    if (i < n && blockIdx.x > 0) offs[i] += bsum[blockIdx.x - 1];
    if (i == n - 1) offs[n] = bsum[nb - 1];
}

__global__ void k_scatter(const int* __restrict__ qidx, const int* __restrict__ kidx,
                          const int* __restrict__ offs, int* __restrict__ cursor,
                          int* __restrict__ skey, int E) {
    int i = blockIdx.x * 256 + threadIdx.x;
    if (i < E) {
        int q = qidx[i];
        int pos = offs[q] + atomicAdd(&cursor[q], 1);
        skey[pos] = kidx[i];
    }
}

// ---------------- per-query softmax aggregation (1 wave / query) ----------------
// No online max: softmax is shift-invariant and |e| is O(10) here, so exp(e)
// is safe in f32. Loop iterations are independent -> unroll x2 for load ILP.
__global__ __launch_bounds__(256) void k_attn(
        const float* __restrict__ Qp, const __bf16* __restrict__ KV,
        const int* __restrict__ offs, const int* __restrict__ skey,
        const float* __restrict__ a, const float* __restrict__ prelu_w,
        float* __restrict__ msg, int NQ_) {
    int lane = threadIdx.x & 63;
    int q = blockIdx.x * 4 + (threadIdx.x >> 6);
    if (q >= NQ_) return;
    int d = lane * 2;
    float a0 = a[d], a1 = a[d + 1];
    float pw = prelu_w[0];
    float q0 = Qp[(size_t)q * DIMN + d], q1 = Qp[(size_t)q * DIMN + d + 1];
    int beg = offs[q], end = offs[q + 1];
    float den = 0.f, acc0 = 0.f, acc1 = 0.f;
    int j = beg;
    for (; j + 1 < end; j += 2) {
        int ka = skey[j], kb = skey[j + 1];
        const uint32_t* ra = (const uint32_t*)(KV + (size_t)ka * 256);
        const uint32_t* rb = (const uint32_t*)(KV + (size_t)kb * 256);
        uint32_t kua = ra[lane], vua = ra[64 + lane];
        uint32_t kub = rb[lane], vub = rb[64 + lane];
        float sa0 = q0 + bf_even(kua), sa1 = q1 + bf_odd(kua);
        sa0 = sa0 >= 0.f ? sa0 : pw * sa0;
        sa1 = sa1 >= 0.f ? sa1 : pw * sa1;
        float ea = a0 * sa0 + a1 * sa1;
        float sb0 = q0 + bf_even(kub), sb1 = q1 + bf_odd(kub);
        sb0 = sb0 >= 0.f ? sb0 : pw * sb0;
        sb1 = sb1 >= 0.f ? sb1 : pw * sb1;
        float eb = a0 * sb0 + a1 * sb1;
        ea += __shfl_xor(ea, 1, 64);  eb += __shfl_xor(eb, 1, 64);
        ea += __shfl_xor(ea, 2, 64);  eb += __shfl_xor(eb, 2, 64);
        ea += __shfl_xor(ea, 4, 64);  eb += __shfl_xor(eb, 4, 64);
        float wa = __expf(ea), wb = __expf(eb);
        den  += wa + wb;
        acc0 += wa * bf_even(vua) + wb * bf_even(vub);
        acc1 += wa * bf_odd(vua)  + wb * bf_odd(vub);
    }
    if (j < end) {
        int k = skey[j];
        const uint32_t* r_ = (const uint32_t*)(KV + (size_t)k * 256);
        uint32_t ku = r_[lane], vu = r_[64 + lane];
        float s0 = q0 + bf_even(ku), s1 = q1 + bf_odd(ku);
        s0 = s0 >= 0.f ? s0 : pw * s0;
        s1 = s1 >= 0.f ? s1 : pw * s1;
        float e = a0 * s0 + a1 * s1;
        e += __shfl_xor(e, 1, 64);
        e += __shfl_xor(e, 2, 64);
        e += __shfl_xor(e, 4, 64);
        float w = __expf(e);
        den  += w;
        acc0 += w * bf_even(vu);
        acc1 += w * bf_odd(vu);
    }
    float inv = den > 0.f ? 1.f / den : 0.f;
    msg[(size_t)q * DIMN + d]     = acc0 * inv;   // msg aliases Qp (row q only)
    msg[(size_t)q * DIMN + d + 1] = acc1 * inv;
}

// ---------------- final: x = query + msg@Wp^T + bp; LayerNorm; write out ----------------
__global__ __launch_bounds__(256) void k_final(
        const float* __restrict__ msg, const __bf16* __restrict__ wh,
        const __bf16* __restrict__ wl, const float* __restrict__ bp,
        const float* __restrict__ query, const float* __restrict__ lng,
        const float* __restrict__ lnb, float* __restrict__ out, int M) {
    int lane = threadIdx.x & 63;
    int wid  = threadIdx.x >> 6;
    int r = lane & 15, g = lane >> 4;
    int rb = blockIdx.x * 64 + wid * 16;

    int arow = rb + r; if (arow >= M) arow = M - 1;
    const float* xrow = msg + (size_t)arow * DIMN;
    bf16x8 Ah[4], Al[4];
#pragma unroll
    for (int ks = 0; ks < 4; ++ks) {
        const float* px = xrow + ks * 32 + g * 8;
#pragma unroll
        for (int i = 0; i < 8; ++i) {
            float v = px[i];
            __bf16 h = (__bf16)v;
            Ah[ks][i] = h;
            Al[ks][i] = (__bf16)(v - (float)h);
        }
    }
    float xv[8][4];
#pragma unroll
    for (int ct = 0; ct < 8; ++ct) {
        f32x4 acc = {0.f, 0.f, 0.f, 0.f};
        int n = ct * 16 + r;
        const __bf16* bh = wh + n * DIMN + g * 8;
        const __bf16* bl = wl + n * DIMN + g * 8;
#pragma unroll
        for (int ks = 0; ks < 4; ++ks) {
            bf16x8 Bh = *(const bf16x8*)(bh + ks * 32);
            bf16x8 Bl = *(const bf16x8*)(bl + ks * 32);
            acc = __builtin_amdgcn_mfma_f32_16x16x32_bf16(Ah[ks], Bh, acc, 0, 0, 0);
            acc = __builtin_amdgcn_mfma_f32_16x16x32_bf16(Ah[ks], Bl, acc, 0, 0, 0);
            acc = __builtin_amdgcn_mfma_f32_16x16x32_bf16(Al[ks], Bh, acc, 0, 0, 0);
        }
        float bn = bp[n];
#pragma unroll
        for (int i = 0; i < 4; ++i) {
            int row = rb + g * 4 + i;
            int rc = row < M ? row : M - 1;
            xv[ct][i] = acc[i] + bn + query[(size_t)rc * DIMN + n];
        }
    }
#pragma unroll
    for (int i = 0; i < 4; ++i) {
        float s = 0.f, ss = 0.f;
#pragma unroll
        for (int ct = 0; ct < 8; ++ct) { s += xv[ct][i]; ss += xv[ct][i] * xv[ct][i]; }
        s += __shfl_xor(s, 1, 64);  ss += __shfl_xor(ss, 1, 64);
        s += __shfl_xor(s, 2, 64);  ss += __shfl_xor(ss, 2, 64);
        s += __shfl_xor(s, 4, 64);  ss += __shfl_xor(ss, 4, 64);
        s += __shfl_xor(s, 8, 64);  ss += __shfl_xor(ss, 8, 64);
        float mean = s * (1.f / DIMN);
        float var  = ss * (1.f / DIMN) - mean * mean;
        float rstd = rsqrtf(var + LN_EPS);
        int row = rb + g * 4 + i;
#pragma unroll
        for (int ct = 0; ct < 8; ++ct) {
            int n = ct * 16 + r;
            if (row < M)
                out[(size_t)row * DIMN + n] = (xv[ct][i] - mean) * rstd * lng[n] + lnb[n];
        }
    }
}

extern "C" void kernel_launch(void* const* d_in, const int* in_sizes, int n_in,
                              void* d_out, int out_size, void* d_ws, size_t ws_size,
                              hipStream_t stream) {
    const float* query = (const float*)d_in[0];
    const float* keys  = (const float*)d_in[1];
    const float* values= (const float*)d_in[2];
    const int*   qidx  = (const int*)d_in[3];
    const int*   kidx  = (const int*)d_in[4];
    const float* Wq    = (const float*)d_in[5];
    const float* bq    = (const float*)d_in[6];
    const float* Wk    = (const float*)d_in[7];
    const float* bk    = (const float*)d_in[8];
    const float* Wv    = (const float*)d_in[9];
    const float* bv    = (const float*)d_in[10];
    const float* Wp    = (const float*)d_in[11];
    const float* bp    = (const float*)d_in[12];
    const float* a     = (const float*)d_in[13];
    const float* pw    = (const float*)d_in[14];
    const float* lng   = (const float*)d_in[15];
    const float* lnb   = (const float*)d_in[16];

    int NQ_ = in_sizes[0] / DIMN;
    int NK_ = in_sizes[1] / DIMN;
    int E_  = in_sizes[3];

    char* p = (char*)d_ws;
    __bf16* wsplit = (__bf16*)p;
    size_t off = (size_t)4 * 32768 * sizeof(__bf16);
    float*  Qp = (float*)(p + off);  off += (size_t)NQ_ * DIMN * 4;
    __bf16* KV = (__bf16*)(p + off); off += (size_t)NK_ * 256 * 2;
    int* counts = (int*)(p + off); off += (((size_t)NQ_ * 4) + 127) / 128 * 128;
    int* cursor = (int*)(p + off); off += (((size_t)NQ_ * 4) + 127) / 128 * 128;
    int* offs   = (int*)(p + off); off += (((size_t)(NQ_ + 1) * 4) + 127) / 128 * 128;
    int* bsum   = (int*)(p + off); off += 1024 * 4;
    int* skey   = (int*)(p + off); off += (size_t)E_ * 4;
    float* msg  = Qp;  // aliasing is safe: wave for query q reads only Qp row q

    hipMemsetAsync(counts, 0, (size_t)NQ_ * 4, stream);
    hipMemsetAsync(cursor, 0, (size_t)NQ_ * 4, stream);

    k_wsplit<<<dim3(64, 4), 256, 0, stream>>>(Wq, Wk, Wv, Wp, wsplit);

    int gm = (NQ_ + 63) / 64;
    int gk = (NK_ + 63) / 64;
    k_proj<float ><<<gm, 256, 0, stream>>>(query,  wsplit + 0*32768, wsplit + 0*32768 + 16384, bq, Qp, NQ_, DIMN, 0);
    k_proj<__bf16><<<gk, 256, 0, stream>>>(keys,   wsplit + 1*32768, wsplit + 1*32768 + 16384, bk, KV, NK_, 256, 0);
    k_proj<__bf16><<<gk, 256, 0, stream>>>(values, wsplit + 2*32768, wsplit + 2*32768 + 16384, bv, KV, NK_, 256, 128);

    int ge = (E_ + 255) / 256;
    int nb = (NQ_ + 255) / 256;
    k_hist<<<ge, 256, 0, stream>>>(qidx, counts, E_);
    k_scan1<<<nb, 256, 0, stream>>>(counts, offs, bsum, NQ_);
    k_scan2<<<1, 1024, 0, stream>>>(bsum, nb);
    k_scan3<<<nb, 256, 0, stream>>>(offs, bsum, NQ_, nb);
    k_scatter<<<ge, 256, 0, stream>>>(qidx, kidx, offs, cursor, skey, E_);

    k_attn<<<(NQ_ + 3) / 4, 256, 0, stream>>>(Qp, KV, offs, skey, a, pw, msg, NQ_);

    k_final<<<gm, 256, 0, stream>>>(msg, wsplit + 3*32768, wsplit + 3*32768 + 16384,
                                    bp, query, lng, lnb, (float*)d_out, NQ_);
}

// Round 3
// 478.478 us; speedup vs baseline: 1.7438x; 1.1567x over previous
//
#include <hip/hip_runtime.h>
#include <hip/hip_bf16.h>

#define DIMN 128
#define LN_EPS 1e-5f

typedef __bf16 bf16x8 __attribute__((ext_vector_type(8)));
typedef float f32x4 __attribute__((ext_vector_type(4)));

__device__ __forceinline__ float bf_even(uint32_t u) {  // element at even dim (low 16 bits)
    union { uint32_t u; float f; } c; c.u = u << 16; return c.f;
}
__device__ __forceinline__ float bf_odd(uint32_t u) {   // element at odd dim (high 16 bits)
    union { uint32_t u; float f; } c; c.u = u & 0xffff0000u; return c.f;
}

// ---------------- K1: W split (blocks 0..255) + hist/rank (rest) ----------------
__global__ __launch_bounds__(256) void k_prep(
        const float* __restrict__ Wq, const float* __restrict__ Wk,
        const float* __restrict__ Wv, const float* __restrict__ Wp,
        __bf16* __restrict__ wsplit, const int* __restrict__ qidx,
        int* __restrict__ counts, int* __restrict__ rank, int E) {
    int bi = blockIdx.x;
    if (bi < 256) {
        int w = bi >> 6;
        const float* W = (w == 0) ? Wq : (w == 1) ? Wk : (w == 2) ? Wv : Wp;
        __bf16* hi = wsplit + (size_t)w * 32768;
        __bf16* lo = hi + 16384;
        int i = (bi & 63) * 256 + threadIdx.x;
        float x = W[i];
        __bf16 h = (__bf16)x;
        hi[i] = h;
        lo[i] = (__bf16)(x - (float)h);
    } else {
        int i = (bi - 256) * 256 + threadIdx.x;
        if (i < E) rank[i] = atomicAdd(&counts[qidx[i]], 1);
    }
}

// ---------------- K2: 3x projection GEMM + scan1 ----------------
// proj: Out[M,128] = X @ W^T + b, 3-term bf16-split MFMA (16x16x32),
// 4 waves/block, 64 rows/block. mode 0 -> f32 Qp; mode 1/2 -> bf16 K/V half.
__global__ __launch_bounds__(256) void k_proj_scan(
        const float* __restrict__ query, const float* __restrict__ keys,
        const float* __restrict__ values, const __bf16* __restrict__ wsplit,
        const float* __restrict__ bq, const float* __restrict__ bk,
        const float* __restrict__ bv, float* __restrict__ Qp,
        __bf16* __restrict__ KV, int NQ_, int NK_,
        const int* __restrict__ counts, int* __restrict__ offs,
        int* __restrict__ bsum, int gm, int gk) {
    __shared__ int s[256];
    int bi = blockIdx.x;
    if (bi < gm + 2 * gk) {
        int mode, rb0, M;
        const float* X; const __bf16* wh; const float* bias;
        if (bi < gm)            { mode = 0; rb0 = bi;            X = query;  wh = wsplit;         bias = bq; M = NQ_; }
        else if (bi < gm + gk)  { mode = 1; rb0 = bi - gm;       X = keys;   wh = wsplit + 32768; bias = bk; M = NK_; }
        else                    { mode = 2; rb0 = bi - gm - gk;  X = values; wh = wsplit + 65536; bias = bv; M = NK_; }
        const __bf16* wl = wh + 16384;

        int lane = threadIdx.x & 63;
        int wid  = threadIdx.x >> 6;
        int r = lane & 15, g = lane >> 4;
        int rb = rb0 * 64 + wid * 16;

        int arow = rb + r; if (arow >= M) arow = M - 1;
        const float* xrow = X + (size_t)arow * DIMN;
        bf16x8 Ah[4], Al[4];
#pragma unroll
        for (int ks = 0; ks < 4; ++ks) {
            const float* px = xrow + ks * 32 + g * 8;
#pragma unroll
            for (int i = 0; i < 8; ++i) {
                float v = px[i];
                __bf16 h = (__bf16)v;
                Ah[ks][i] = h;
                Al[ks][i] = (__bf16)(v - (float)h);
            }
        }
#pragma unroll
        for (int ct = 0; ct < 8; ++ct) {
            f32x4 acc = {0.f, 0.f, 0.f, 0.f};
            int n = ct * 16 + r;
            const __bf16* bh = wh + n * DIMN + g * 8;
            const __bf16* bl = wl + n * DIMN + g * 8;
#pragma unroll
            for (int ks = 0; ks < 4; ++ks) {
                bf16x8 Bh = *(const bf16x8*)(bh + ks * 32);
                bf16x8 Bl = *(const bf16x8*)(bl + ks * 32);
                acc = __builtin_amdgcn_mfma_f32_16x16x32_bf16(Ah[ks], Bh, acc, 0, 0, 0);
                acc = __builtin_amdgcn_mfma_f32_16x16x32_bf16(Ah[ks], Bl, acc, 0, 0, 0);
                acc = __builtin_amdgcn_mfma_f32_16x16x32_bf16(Al[ks], Bh, acc, 0, 0, 0);
            }
            float bn = bias[n];
#pragma unroll
            for (int i = 0; i < 4; ++i) {
                int row = rb + g * 4 + i;
                if (row < M) {
                    float v = acc[i] + bn;
                    if (mode == 0) Qp[(size_t)row * DIMN + n] = v;
                    else KV[(size_t)row * 256 + (mode == 2 ? 128 : 0) + n] = (__bf16)v;
                }
            }
        }
    } else {
        // scan1: per-block exclusive prefix + block sum
        int b = bi - (gm + 2 * gk);
        int t = threadIdx.x;
        int i = b * 256 + t;
        int v = (i < NQ_) ? counts[i] : 0;
        s[t] = v;
        __syncthreads();
        for (int o = 1; o < 256; o <<= 1) {
            int x = (t >= o) ? s[t - o] : 0;
            __syncthreads();
            s[t] += x;
            __syncthreads();
        }
        if (i < NQ_) offs[i] = s[t] - v;
        if (t == 255) bsum[b] = s[t];
    }
}

__global__ __launch_bounds__(1024) void k_scan2(int* __restrict__ bsum, int nb) {
    __shared__ int s[1024];
    int t = threadIdx.x;
    int v = (t < nb) ? bsum[t] : 0;
    s[t] = v;
    __syncthreads();
    for (int o = 1; o < 1024; o <<= 1) {
        int x = (t >= o) ? s[t - o] : 0;
        __syncthreads();
        s[t] += x;
        __syncthreads();
    }
    if (t < nb) bsum[t] = s[t];  // inclusive block-sum scan
}

// final offset of query i = offs[i] + (i>=256 ? bsum[i/256-1] : 0)
__global__ void k_scatter(const int* __restrict__ qidx, const int* __restrict__ kidx,
                          const int* __restrict__ offs, const int* __restrict__ bsum,
                          const int* __restrict__ rank, int* __restrict__ skey, int E) {
    int i = blockIdx.x * 256 + threadIdx.x;
    if (i < E) {
        int q = qidx[i];
        int base = offs[q] + ((q >= 256) ? bsum[(q >> 8) - 1] : 0);
        skey[base + rank[i]] = kidx[i];
    }
}

// ---------------- per-query softmax aggregation (1 wave / query) ----------------
// No online max (softmax shift-invariance; |e| is O(10), exp safe in f32).
// Unroll x4: 8 independent gathers in flight per wave.
__global__ __launch_bounds__(256) void k_attn(
        const float* __restrict__ Qp, const __bf16* __restrict__ KV,
        const int* __restrict__ offs, const int* __restrict__ bsum,
        const int* __restrict__ skey, const float* __restrict__ a,
        const float* __restrict__ prelu_w, float* __restrict__ msg,
        int NQ_, int E_) {
    int lane = threadIdx.x & 63;
    int q = blockIdx.x * 4 + (threadIdx.x >> 6);
    if (q >= NQ_) return;
    int d = lane * 2;
    float2 av = *(const float2*)(a + d);
    float a0 = av.x, a1 = av.y;
    float pw = prelu_w[0];
    float2 qv = *(const float2*)(Qp + (size_t)q * DIMN + d);
    float q0 = qv.x, q1 = qv.y;
    int beg = offs[q] + ((q >= 256) ? bsum[(q >> 8) - 1] : 0);
    int qn = q + 1;
    int end = (qn == NQ_) ? E_ : offs[qn] + ((qn >= 256) ? bsum[(qn >> 8) - 1] : 0);

    float den = 0.f, acc0 = 0.f, acc1 = 0.f;
    int j = beg;
    for (; j + 3 < end; j += 4) {
        int k0 = skey[j], k1 = skey[j + 1], k2 = skey[j + 2], k3 = skey[j + 3];
        const uint32_t* r0 = (const uint32_t*)(KV + ((size_t)k0 << 8));
        const uint32_t* r1 = (const uint32_t*)(KV + ((size_t)k1 << 8));
        const uint32_t* r2 = (const uint32_t*)(KV + ((size_t)k2 << 8));
        const uint32_t* r3 = (const uint32_t*)(KV + ((size_t)k3 << 8));
        uint32_t ku0 = r0[lane], ku1 = r1[lane], ku2 = r2[lane], ku3 = r3[lane];
        uint32_t vu0 = r0[64 + lane], vu1 = r1[64 + lane], vu2 = r2[64 + lane], vu3 = r3[64 + lane];

        float e0, e1, e2, e3;
        {
            float s0 = q0 + bf_even(ku0), s1 = q1 + bf_odd(ku0);
            s0 = s0 >= 0.f ? s0 : pw * s0;  s1 = s1 >= 0.f ? s1 : pw * s1;
            e0 = a0 * s0 + a1 * s1;
        }
        {
            float s0 = q0 + bf_even(ku1), s1 = q1 + bf_odd(ku1);
            s0 = s0 >= 0.f ? s0 : pw * s0;  s1 = s1 >= 0.f ? s1 : pw * s1;
            e1 = a0 * s0 + a1 * s1;
        }
        {
            float s0 = q0 + bf_even(ku2), s1 = q1 + bf_odd(ku2);
            s0 = s0 >= 0.f ? s0 : pw * s0;  s1 = s1 >= 0.f ? s1 : pw * s1;
            e2 = a0 * s0 + a1 * s1;
        }
        {
            float s0 = q0 + bf_even(ku3), s1 = q1 + bf_odd(ku3);
            s0 = s0 >= 0.f ? s0 : pw * s0;  s1 = s1 >= 0.f ? s1 : pw * s1;
            e3 = a0 * s0 + a1 * s1;
        }
        e0 += __shfl_xor(e0, 1, 64); e1 += __shfl_xor(e1, 1, 64);
        e2 += __shfl_xor(e2, 1, 64); e3 += __shfl_xor(e3, 1, 64);
        e0 += __shfl_xor(e0, 2, 64); e1 += __shfl_xor(e1, 2, 64);
        e2 += __shfl_xor(e2, 2, 64); e3 += __shfl_xor(e3, 2, 64);
        e0 += __shfl_xor(e0, 4, 64); e1 += __shfl_xor(e1, 4, 64);
        e2 += __shfl_xor(e2, 4, 64); e3 += __shfl_xor(e3, 4, 64);
        float w0 = __expf(e0), w1 = __expf(e1), w2 = __expf(e2), w3 = __expf(e3);
        den  += (w0 + w1) + (w2 + w3);
        acc0 += w0 * bf_even(vu0) + w1 * bf_even(vu1) + w2 * bf_even(vu2) + w3 * bf_even(vu3);
        acc1 += w0 * bf_odd(vu0)  + w1 * bf_odd(vu1)  + w2 * bf_odd(vu2)  + w3 * bf_odd(vu3);
    }
    for (; j < end; ++j) {
        int k = skey[j];
        const uint32_t* r_ = (const uint32_t*)(KV + ((size_t)k << 8));
        uint32_t ku = r_[lane], vu = r_[64 + lane];
        float s0 = q0 + bf_even(ku), s1 = q1 + bf_odd(ku);
        s0 = s0 >= 0.f ? s0 : pw * s0;  s1 = s1 >= 0.f ? s1 : pw * s1;
        float e = a0 * s0 + a1 * s1;
        e += __shfl_xor(e, 1, 64);
        e += __shfl_xor(e, 2, 64);
        e += __shfl_xor(e, 4, 64);
        float w = __expf(e);
        den += w;
        acc0 += w * bf_even(vu);
        acc1 += w * bf_odd(vu);
    }
    float inv = den > 0.f ? 1.f / den : 0.f;
    float2 o; o.x = acc0 * inv; o.y = acc1 * inv;
    *(float2*)(msg + (size_t)q * DIMN + d) = o;   // msg aliases Qp (row q only)
}

// ---------------- final: x = query + msg@Wp^T + bp; LayerNorm ----------------
__global__ __launch_bounds__(256) void k_final(
        const float* __restrict__ msg, const __bf16* __restrict__ wh,
        const __bf16* __restrict__ wl, const float* __restrict__ bp,
        const float* __restrict__ query, const float* __restrict__ lng,
        const float* __restrict__ lnb, float* __restrict__ out, int M) {
    int lane = threadIdx.x & 63;
    int wid  = threadIdx.x >> 6;
    int r = lane & 15, g = lane >> 4;
    int rb = blockIdx.x * 64 + wid * 16;

    int arow = rb + r; if (arow >= M) arow = M - 1;
    const float* xrow = msg + (size_t)arow * DIMN;
    bf16x8 Ah[4], Al[4];
#pragma unroll
    for (int ks = 0; ks < 4; ++ks) {
        const float* px = xrow + ks * 32 + g * 8;
#pragma unroll
        for (int i = 0; i < 8; ++i) {
            float v = px[i];
            __bf16 h = (__bf16)v;
            Ah[ks][i] = h;
            Al[ks][i] = (__bf16)(v - (float)h);
        }
    }
    float xv[8][4];
#pragma unroll
    for (int ct = 0; ct < 8; ++ct) {
        f32x4 acc = {0.f, 0.f, 0.f, 0.f};
        int n = ct * 16 + r;
        const __bf16* bh = wh + n * DIMN + g * 8;
        const __bf16* bl = wl + n * DIMN + g * 8;
#pragma unroll
        for (int ks = 0; ks < 4; ++ks) {
            bf16x8 Bh = *(const bf16x8*)(bh + ks * 32);
            bf16x8 Bl = *(const bf16x8*)(bl + ks * 32);
            acc = __builtin_amdgcn_mfma_f32_16x16x32_bf16(Ah[ks], Bh, acc, 0, 0, 0);
            acc = __builtin_amdgcn_mfma_f32_16x16x32_bf16(Ah[ks], Bl, acc, 0, 0, 0);
            acc = __builtin_amdgcn_mfma_f32_16x16x32_bf16(Al[ks], Bh, acc, 0, 0, 0);
        }
        float bn = bp[n];
#pragma unroll
        for (int i = 0; i < 4; ++i) {
            int row = rb + g * 4 + i;
            int rc = row < M ? row : M - 1;
            xv[ct][i] = acc[i] + bn + query[(size_t)rc * DIMN + n];
        }
    }
#pragma unroll
    for (int i = 0; i < 4; ++i) {
        float s = 0.f, ss = 0.f;
#pragma unroll
        for (int ct = 0; ct < 8; ++ct) { s += xv[ct][i]; ss += xv[ct][i] * xv[ct][i]; }
        s += __shfl_xor(s, 1, 64);  ss += __shfl_xor(ss, 1, 64);
        s += __shfl_xor(s, 2, 64);  ss += __shfl_xor(ss, 2, 64);
        s += __shfl_xor(s, 4, 64);  ss += __shfl_xor(ss, 4, 64);
        s += __shfl_xor(s, 8, 64);  ss += __shfl_xor(ss, 8, 64);
        float mean = s * (1.f / DIMN);
        float var  = ss * (1.f / DIMN) - mean * mean;
        float rstd = rsqrtf(var + LN_EPS);
        int row = rb + g * 4 + i;
#pragma unroll
        for (int ct = 0; ct < 8; ++ct) {
            int n = ct * 16 + r;
            if (row < M)
                out[(size_t)row * DIMN + n] = (xv[ct][i] - mean) * rstd * lng[n] + lnb[n];
        }
    }
}

extern "C" void kernel_launch(void* const* d_in, const int* in_sizes, int n_in,
                              void* d_out, int out_size, void* d_ws, size_t ws_size,
                              hipStream_t stream) {
    const float* query = (const float*)d_in[0];
    const float* keys  = (const float*)d_in[1];
    const float* values= (const float*)d_in[2];
    const int*   qidx  = (const int*)d_in[3];
    const int*   kidx  = (const int*)d_in[4];
    const float* Wq    = (const float*)d_in[5];
    const float* bq    = (const float*)d_in[6];
    const float* Wk    = (const float*)d_in[7];
    const float* bk    = (const float*)d_in[8];
    const float* Wv    = (const float*)d_in[9];
    const float* bv    = (const float*)d_in[10];
    const float* Wp    = (const float*)d_in[11];
    const float* bp    = (const float*)d_in[12];
    const float* a     = (const float*)d_in[13];
    const float* pw    = (const float*)d_in[14];
    const float* lng   = (const float*)d_in[15];
    const float* lnb   = (const float*)d_in[16];

    int NQ_ = in_sizes[0] / DIMN;
    int NK_ = in_sizes[1] / DIMN;
    int E_  = in_sizes[3];

    char* p = (char*)d_ws;
    __bf16* wsplit = (__bf16*)p;
    size_t off = (size_t)4 * 32768 * sizeof(__bf16);
    float*  Qp = (float*)(p + off);  off += (size_t)NQ_ * DIMN * 4;
    __bf16* KV = (__bf16*)(p + off); off += (size_t)NK_ * 256 * 2;
    int* counts = (int*)(p + off); off += (((size_t)NQ_ * 4) + 127) / 128 * 128;
    int* offs   = (int*)(p + off); off += (((size_t)NQ_ * 4) + 127) / 128 * 128;
    int* bsum   = (int*)(p + off); off += 1024 * 4;
    int* rank   = (int*)(p + off); off += (size_t)E_ * 4;
    int* skey   = (int*)(p + off); off += (size_t)E_ * 4;
    float* msg  = Qp;  // aliasing is safe: wave for query q reads only Qp row q

    hipMemsetAsync(counts, 0, (size_t)NQ_ * 4, stream);

    int ge = (E_ + 255) / 256;
    int gm = (NQ_ + 63) / 64;
    int gk = (NK_ + 63) / 64;
    int nb = (NQ_ + 255) / 256;

    k_prep<<<256 + ge, 256, 0, stream>>>(Wq, Wk, Wv, Wp, wsplit, qidx, counts, rank, E_);

    k_proj_scan<<<gm + 2 * gk + nb, 256, 0, stream>>>(
        query, keys, values, wsplit, bq, bk, bv, Qp, KV, NQ_, NK_,
        counts, offs, bsum, gm, gk);

    k_scan2<<<1, 1024, 0, stream>>>(bsum, nb);

    k_scatter<<<ge, 256, 0, stream>>>(qidx, kidx, offs, bsum, rank, skey, E_);

    k_attn<<<(NQ_ + 3) / 4, 256, 0, stream>>>(Qp, KV, offs, bsum, skey, a, pw, msg, NQ_, E_);

    k_final<<<gm, 256, 0, stream>>>(msg, wsplit + 3 * 32768, wsplit + 3 * 32768 + 16384,
                                    bp, query, lng, lnb, (float*)d_out, NQ_);
}

// Round 4
// 439.178 us; speedup vs baseline: 1.8999x; 1.0895x over previous
//
#include <hip/hip_runtime.h>
#include <hip/hip_bf16.h>

#define DIMN 128
#define LN_EPS 1e-5f

typedef __bf16 bf16x8 __attribute__((ext_vector_type(8)));
typedef float f32x4 __attribute__((ext_vector_type(4)));

__device__ __forceinline__ float bf_even(uint32_t u) {  // element at even dim (low 16 bits)
    union { uint32_t u; float f; } c; c.u = u << 16; return c.f;
}
__device__ __forceinline__ float bf_odd(uint32_t u) {   // element at odd dim (high 16 bits)
    union { uint32_t u; float f; } c; c.u = u & 0xffff0000u; return c.f;
}

// ---------------- K1: W split (blocks 0..255) + hist/rank (rest) ----------------
__global__ __launch_bounds__(256) void k_prep(
        const float* __restrict__ Wq, const float* __restrict__ Wk,
        const float* __restrict__ Wv, const float* __restrict__ Wp,
        __bf16* __restrict__ wsplit, const int* __restrict__ qidx,
        int* __restrict__ counts, int* __restrict__ rank, int E) {
    int bi = blockIdx.x;
    if (bi < 256) {
        int w = bi >> 6;
        const float* W = (w == 0) ? Wq : (w == 1) ? Wk : (w == 2) ? Wv : Wp;
        __bf16* hi = wsplit + (size_t)w * 32768;
        __bf16* lo = hi + 16384;
        int i = (bi & 63) * 256 + threadIdx.x;
        float x = W[i];
        __bf16 h = (__bf16)x;
        hi[i] = h;
        lo[i] = (__bf16)(x - (float)h);
    } else {
        int i = (bi - 256) * 256 + threadIdx.x;
        if (i < E) rank[i] = atomicAdd(&counts[qidx[i]], 1);
    }
}

// ---------------- K2: persistent-grid projections (+ scan1 in low blocks) -----
// W fragments live in registers: each wave owns a 64-col half (hi+lo = 32 x
// bf16x8 = 64 VGPR) and grid-strides over 32-row tiles, mode-major order so
// B reloads happen at most ~3x per block. Block = 4 waves = 32 rows x 128 cols.
__global__ __launch_bounds__(256) void k_proj2(
        const float* __restrict__ query, const float* __restrict__ keys,
        const float* __restrict__ values, const __bf16* __restrict__ wsplit,
        const float* __restrict__ bq, const float* __restrict__ bk,
        const float* __restrict__ bv, float* __restrict__ Qp,
        __bf16* __restrict__ KV, int NQ_, int NK_,
        const int* __restrict__ counts, int* __restrict__ offs,
        int* __restrict__ bsum, int nb) {
    __shared__ int s[256];
    // ---- scan1 piggyback (counts ready: k_prep ran before) ----
    if ((int)blockIdx.x < nb) {
        int t = threadIdx.x;
        int i = blockIdx.x * 256 + t;
        int v = (i < NQ_) ? counts[i] : 0;
        s[t] = v;
        __syncthreads();
        for (int o = 1; o < 256; o <<= 1) {
            int x = (t >= o) ? s[t - o] : 0;
            __syncthreads();
            s[t] += x;
            __syncthreads();
        }
        if (i < NQ_) offs[i] = s[t] - v;
        if (t == 255) bsum[blockIdx.x] = s[t];
    }

    int lane = threadIdx.x & 63;
    int wid  = threadIdx.x >> 6;
    int r = lane & 15, g = lane >> 4;
    int rowoff = (wid >> 1) * 16;   // 0 or 16 within the 32-row tile
    int chalf  = wid & 1;           // column half: cols [chalf*64, chalf*64+64)

    int ntq = (NQ_ + 31) >> 5;
    int ntk = (NK_ + 31) >> 5;
    int total = ntq + 2 * ntk;

    int mode = -1;
    bf16x8 Bf[4][4][2];             // [ct][ks][hi/lo] -- 64 VGPR, persistent
    float  bias_n[4];

    for (int t = blockIdx.x; t < total; t += gridDim.x) {
        int m, tt;
        if (t < ntq)            { m = 0; tt = t; }
        else if (t < ntq + ntk) { m = 1; tt = t - ntq; }
        else                    { m = 2; tt = t - ntq - ntk; }

        if (m != mode) {
            mode = m;
            const __bf16* wh = wsplit + (size_t)m * 32768;
            const __bf16* wl = wh + 16384;
            const float* bias = (m == 0) ? bq : (m == 1) ? bk : bv;
#pragma unroll
            for (int c = 0; c < 4; ++c) {
                int n = (chalf * 4 + c) * 16 + r;
#pragma unroll
                for (int ks = 0; ks < 4; ++ks) {
                    Bf[c][ks][0] = *(const bf16x8*)(wh + n * DIMN + ks * 32 + g * 8);
                    Bf[c][ks][1] = *(const bf16x8*)(wl + n * DIMN + ks * 32 + g * 8);
                }
                bias_n[c] = bias[n];
            }
        }

        const float* X = (m == 0) ? query : (m == 1) ? keys : values;
        int M = (m == 0) ? NQ_ : NK_;
        int rb = tt * 32 + rowoff;
        int arow = rb + r; if (arow >= M) arow = M - 1;
        const float* xrow = X + (size_t)arow * DIMN;

        bf16x8 Ah[4], Al[4];
#pragma unroll
        for (int ks = 0; ks < 4; ++ks) {
            const float* px = xrow + ks * 32 + g * 8;
#pragma unroll
            for (int i = 0; i < 8; ++i) {
                float v = px[i];
                __bf16 h = (__bf16)v;
                Ah[ks][i] = h;
                Al[ks][i] = (__bf16)(v - (float)h);
            }
        }

        f32x4 acc[4];
#pragma unroll
        for (int c = 0; c < 4; ++c) {
            acc[c] = (f32x4){0.f, 0.f, 0.f, 0.f};
#pragma unroll
            for (int ks = 0; ks < 4; ++ks) {
                acc[c] = __builtin_amdgcn_mfma_f32_16x16x32_bf16(Ah[ks], Bf[c][ks][0], acc[c], 0, 0, 0);
                acc[c] = __builtin_amdgcn_mfma_f32_16x16x32_bf16(Ah[ks], Bf[c][ks][1], acc[c], 0, 0, 0);
                acc[c] = __builtin_amdgcn_mfma_f32_16x16x32_bf16(Al[ks], Bf[c][ks][0], acc[c], 0, 0, 0);
            }
        }

        if (m == 0) {
#pragma unroll
            for (int c = 0; c < 4; ++c) {
                int n = (chalf * 4 + c) * 16 + r;
#pragma unroll
                for (int i = 0; i < 4; ++i) {
                    int row = rb + g * 4 + i;
                    if (row < M) Qp[(size_t)row * DIMN + n] = acc[c][i] + bias_n[c];
                }
            }
        } else {
            int vofs = (m == 2) ? 128 : 0;
#pragma unroll
            for (int c = 0; c < 4; ++c) {
                int n = (chalf * 4 + c) * 16 + r;
#pragma unroll
                for (int i = 0; i < 4; ++i) {
                    int row = rb + g * 4 + i;
                    if (row < M) KV[(size_t)row * 256 + vofs + n] = (__bf16)(acc[c][i] + bias_n[c]);
                }
            }
        }
    }
}

__global__ __launch_bounds__(1024) void k_scan2(int* __restrict__ bsum, int nb) {
    __shared__ int s[1024];
    int t = threadIdx.x;
    int v = (t < nb) ? bsum[t] : 0;
    s[t] = v;
    __syncthreads();
    for (int o = 1; o < 1024; o <<= 1) {
        int x = (t >= o) ? s[t - o] : 0;
        __syncthreads();
        s[t] += x;
        __syncthreads();
    }
    if (t < nb) bsum[t] = s[t];  // inclusive block-sum scan
}

// final offset of query i = offs[i] + (i>=256 ? bsum[i/256-1] : 0)
__global__ void k_scatter(const int* __restrict__ qidx, const int* __restrict__ kidx,
                          const int* __restrict__ offs, const int* __restrict__ bsum,
                          const int* __restrict__ rank, int* __restrict__ skey, int E) {
    int i = blockIdx.x * 256 + threadIdx.x;
    if (i < E) {
        int q = qidx[i];
        int base = offs[q] + ((q >= 256) ? bsum[(q >> 8) - 1] : 0);
        skey[base + rank[i]] = kidx[i];
    }
}

// ---------------- per-query softmax aggregation (1 wave / query) ----------------
__global__ __launch_bounds__(256) void k_attn(
        const float* __restrict__ Qp, const __bf16* __restrict__ KV,
        const int* __restrict__ offs, const int* __restrict__ bsum,
        const int* __restrict__ skey, const float* __restrict__ a,
        const float* __restrict__ prelu_w, float* __restrict__ msg,
        int NQ_, int E_) {
    int lane = threadIdx.x & 63;
    int q = blockIdx.x * 4 + (threadIdx.x >> 6);
    if (q >= NQ_) return;
    int d = lane * 2;
    float2 av = *(const float2*)(a + d);
    float a0 = av.x, a1 = av.y;
    float pw = prelu_w[0];
    float2 qv = *(const float2*)(Qp + (size_t)q * DIMN + d);
    float q0 = qv.x, q1 = qv.y;
    int beg = offs[q] + ((q >= 256) ? bsum[(q >> 8) - 1] : 0);
    int qn = q + 1;
    int end = (qn == NQ_) ? E_ : offs[qn] + ((qn >= 256) ? bsum[(qn >> 8) - 1] : 0);

    float den = 0.f, acc0 = 0.f, acc1 = 0.f;
    int j = beg;
    for (; j + 3 < end; j += 4) {
        int k0 = skey[j], k1 = skey[j + 1], k2 = skey[j + 2], k3 = skey[j + 3];
        const uint32_t* r0 = (const uint32_t*)(KV + ((size_t)k0 << 8));
        const uint32_t* r1 = (const uint32_t*)(KV + ((size_t)k1 << 8));
        const uint32_t* r2 = (const uint32_t*)(KV + ((size_t)k2 << 8));
        const uint32_t* r3 = (const uint32_t*)(KV + ((size_t)k3 << 8));
        uint32_t ku0 = r0[lane], ku1 = r1[lane], ku2 = r2[lane], ku3 = r3[lane];
        uint32_t vu0 = r0[64 + lane], vu1 = r1[64 + lane], vu2 = r2[64 + lane], vu3 = r3[64 + lane];

        float e0, e1, e2, e3;
        {
            float s0 = q0 + bf_even(ku0), s1 = q1 + bf_odd(ku0);
            s0 = s0 >= 0.f ? s0 : pw * s0;  s1 = s1 >= 0.f ? s1 : pw * s1;
            e0 = a0 * s0 + a1 * s1;
        }
        {
            float s0 = q0 + bf_even(ku1), s1 = q1 + bf_odd(ku1);
            s0 = s0 >= 0.f ? s0 : pw * s0;  s1 = s1 >= 0.f ? s1 : pw * s1;
            e1 = a0 * s0 + a1 * s1;
        }
        {
            float s0 = q0 + bf_even(ku2), s1 = q1 + bf_odd(ku2);
            s0 = s0 >= 0.f ? s0 : pw * s0;  s1 = s1 >= 0.f ? s1 : pw * s1;
            e2 = a0 * s0 + a1 * s1;
        }
        {
            float s0 = q0 + bf_even(ku3), s1 = q1 + bf_odd(ku3);
            s0 = s0 >= 0.f ? s0 : pw * s0;  s1 = s1 >= 0.f ? s1 : pw * s1;
            e3 = a0 * s0 + a1 * s1;
        }
        e0 += __shfl_xor(e0, 1, 64); e1 += __shfl_xor(e1, 1, 64);
        e2 += __shfl_xor(e2, 1, 64); e3 += __shfl_xor(e3, 1, 64);
        e0 += __shfl_xor(e0, 2, 64); e1 += __shfl_xor(e1, 2, 64);
        e2 += __shfl_xor(e2, 2, 64); e3 += __shfl_xor(e3, 2, 64);
        e0 += __shfl_xor(e0, 4, 64); e1 += __shfl_xor(e1, 4, 64);
        e2 += __shfl_xor(e2, 4, 64); e3 += __shfl_xor(e3, 4, 64);
        float w0 = __expf(e0), w1 = __expf(e1), w2 = __expf(e2), w3 = __expf(e3);
        den  += (w0 + w1) + (w2 + w3);
        acc0 += w0 * bf_even(vu0) + w1 * bf_even(vu1) + w2 * bf_even(vu2) + w3 * bf_even(vu3);
        acc1 += w0 * bf_odd(vu0)  + w1 * bf_odd(vu1)  + w2 * bf_odd(vu2)  + w3 * bf_odd(vu3);
    }
    for (; j < end; ++j) {
        int k = skey[j];
        const uint32_t* r_ = (const uint32_t*)(KV + ((size_t)k << 8));
        uint32_t ku = r_[lane], vu = r_[64 + lane];
        float s0 = q0 + bf_even(ku), s1 = q1 + bf_odd(ku);
        s0 = s0 >= 0.f ? s0 : pw * s0;  s1 = s1 >= 0.f ? s1 : pw * s1;
        float e = a0 * s0 + a1 * s1;
        e += __shfl_xor(e, 1, 64);
        e += __shfl_xor(e, 2, 64);
        e += __shfl_xor(e, 4, 64);
        float w = __expf(e);
        den += w;
        acc0 += w * bf_even(vu);
        acc1 += w * bf_odd(vu);
    }
    float inv = den > 0.f ? 1.f / den : 0.f;
    float2 o; o.x = acc0 * inv; o.y = acc1 * inv;
    *(float2*)(msg + (size_t)q * DIMN + d) = o;   // msg aliases Qp (row q only)
}

// ---------------- final: x = query + msg@Wp^T + bp; LayerNorm ----------------
__global__ __launch_bounds__(256) void k_final(
        const float* __restrict__ msg, const __bf16* __restrict__ wh,
        const __bf16* __restrict__ wl, const float* __restrict__ bp,
        const float* __restrict__ query, const float* __restrict__ lng,
        const float* __restrict__ lnb, float* __restrict__ out, int M) {
    int lane = threadIdx.x & 63;
    int wid  = threadIdx.x >> 6;
    int r = lane & 15, g = lane >> 4;
    int rb = blockIdx.x * 64 + wid * 16;

    int arow = rb + r; if (arow >= M) arow = M - 1;
    const float* xrow = msg + (size_t)arow * DIMN;
    bf16x8 Ah[4], Al[4];
#pragma unroll
    for (int ks = 0; ks < 4; ++ks) {
        const float* px = xrow + ks * 32 + g * 8;
#pragma unroll
        for (int i = 0; i < 8; ++i) {
            float v = px[i];
            __bf16 h = (__bf16)v;
            Ah[ks][i] = h;
            Al[ks][i] = (__bf16)(v - (float)h);
        }
    }
    float xv[8][4];
#pragma unroll
    for (int ct = 0; ct < 8; ++ct) {
        f32x4 acc = {0.f, 0.f, 0.f, 0.f};
        int n = ct * 16 + r;
        const __bf16* bh = wh + n * DIMN + g * 8;
        const __bf16* bl = wl + n * DIMN + g * 8;
#pragma unroll
        for (int ks = 0; ks < 4; ++ks) {
            bf16x8 Bh = *(const bf16x8*)(bh + ks * 32);
            bf16x8 Bl = *(const bf16x8*)(bl + ks * 32);
            acc = __builtin_amdgcn_mfma_f32_16x16x32_bf16(Ah[ks], Bh, acc, 0, 0, 0);
            acc = __builtin_amdgcn_mfma_f32_16x16x32_bf16(Ah[ks], Bl, acc, 0, 0, 0);
            acc = __builtin_amdgcn_mfma_f32_16x16x32_bf16(Al[ks], Bh, acc, 0, 0, 0);
        }
        float bn = bp[n];
#pragma unroll
        for (int i = 0; i < 4; ++i) {
            int row = rb + g * 4 + i;
            int rc = row < M ? row : M - 1;
            xv[ct][i] = acc[i] + bn + query[(size_t)rc * DIMN + n];
        }
    }
#pragma unroll
    for (int i = 0; i < 4; ++i) {
        float s = 0.f, ss = 0.f;
#pragma unroll
        for (int ct = 0; ct < 8; ++ct) { s += xv[ct][i]; ss += xv[ct][i] * xv[ct][i]; }
        s += __shfl_xor(s, 1, 64);  ss += __shfl_xor(ss, 1, 64);
        s += __shfl_xor(s, 2, 64);  ss += __shfl_xor(ss, 2, 64);
        s += __shfl_xor(s, 4, 64);  ss += __shfl_xor(ss, 4, 64);
        s += __shfl_xor(s, 8, 64);  ss += __shfl_xor(ss, 8, 64);
        float mean = s * (1.f / DIMN);
        float var  = ss * (1.f / DIMN) - mean * mean;
        float rstd = rsqrtf(var + LN_EPS);
        int row = rb + g * 4 + i;
#pragma unroll
        for (int ct = 0; ct < 8; ++ct) {
            int n = ct * 16 + r;
            if (row < M)
                out[(size_t)row * DIMN + n] = (xv[ct][i] - mean) * rstd * lng[n] + lnb[n];
        }
    }
}

extern "C" void kernel_launch(void* const* d_in, const int* in_sizes, int n_in,
                              void* d_out, int out_size, void* d_ws, size_t ws_size,
                              hipStream_t stream) {
    const float* query = (const float*)d_in[0];
    const float* keys  = (const float*)d_in[1];
    const float* values= (const float*)d_in[2];
    const int*   qidx  = (const int*)d_in[3];
    const int*   kidx  = (const int*)d_in[4];
    const float* Wq    = (const float*)d_in[5];
    const float* bq    = (const float*)d_in[6];
    const float* Wk    = (const float*)d_in[7];
    const float* bk    = (const float*)d_in[8];
    const float* Wv    = (const float*)d_in[9];
    const float* bv    = (const float*)d_in[10];
    const float* Wp    = (const float*)d_in[11];
    const float* bp    = (const float*)d_in[12];
    const float* a     = (const float*)d_in[13];
    const float* pw    = (const float*)d_in[14];
    const float* lng   = (const float*)d_in[15];
    const float* lnb   = (const float*)d_in[16];

    int NQ_ = in_sizes[0] / DIMN;
    int NK_ = in_sizes[1] / DIMN;
    int E_  = in_sizes[3];

    char* p = (char*)d_ws;
    __bf16* wsplit = (__bf16*)p;
    size_t off = (size_t)4 * 32768 * sizeof(__bf16);
    float*  Qp = (float*)(p + off);  off += (size_t)NQ_ * DIMN * 4;
    __bf16* KV = (__bf16*)(p + off); off += (size_t)NK_ * 256 * 2;
    int* counts = (int*)(p + off); off += (((size_t)NQ_ * 4) + 127) / 128 * 128;
    int* offs   = (int*)(p + off); off += (((size_t)NQ_ * 4) + 127) / 128 * 128;
    int* bsum   = (int*)(p + off); off += 1024 * 4;
    int* rank   = (int*)(p + off); off += (size_t)E_ * 4;
    int* skey   = (int*)(p + off); off += (size_t)E_ * 4;
    float* msg  = Qp;  // aliasing is safe: wave for query q reads only Qp row q

    hipMemsetAsync(counts, 0, (size_t)NQ_ * 4, stream);

    int ge = (E_ + 255) / 256;
    int gm = (NQ_ + 63) / 64;
    int nb = (NQ_ + 255) / 256;

    k_prep<<<256 + ge, 256, 0, stream>>>(Wq, Wk, Wv, Wp, wsplit, qidx, counts, rank, E_);

    k_proj2<<<2048, 256, 0, stream>>>(query, keys, values, wsplit, bq, bk, bv,
                                      Qp, KV, NQ_, NK_, counts, offs, bsum, nb);

    k_scan2<<<1, 1024, 0, stream>>>(bsum, nb);

    k_scatter<<<ge, 256, 0, stream>>>(qidx, kidx, offs, bsum, rank, skey, E_);

    k_attn<<<(NQ_ + 3) / 4, 256, 0, stream>>>(Qp, KV, offs, bsum, skey, a, pw, msg, NQ_, E_);

    k_final<<<gm, 256, 0, stream>>>(msg, wsplit + 3 * 32768, wsplit + 3 * 32768 + 16384,
                                    bp, query, lng, lnb, (float*)d_out, NQ_);
}

// Round 5
// 435.692 us; speedup vs baseline: 1.9151x; 1.0080x over previous
//
#include <hip/hip_runtime.h>
#include <hip/hip_bf16.h>

#define DIMN 128
#define LN_EPS 1e-5f

typedef __bf16 bf16x8 __attribute__((ext_vector_type(8)));
typedef float f32x4 __attribute__((ext_vector_type(4)));

__device__ __forceinline__ float bf_even(uint32_t u) {  // element at even dim (low 16 bits)
    union { uint32_t u; float f; } c; c.u = u << 16; return c.f;
}
__device__ __forceinline__ float bf_odd(uint32_t u) {   // element at odd dim (high 16 bits)
    union { uint32_t u; float f; } c; c.u = u & 0xffff0000u; return c.f;
}

// 8-lane xor-reduction via ds_swizzle (no address VALU, 1 LDS-pipe op each).
// BitMode offsets: xor1=0x041F, xor2=0x081F, xor4=0x101F (ISA doc pattern).
__device__ __forceinline__ float head_reduce(float e) {
    int x = __float_as_int(e);
    e += __int_as_float(__builtin_amdgcn_ds_swizzle(x, 0x041F));
    x = __float_as_int(e);
    e += __int_as_float(__builtin_amdgcn_ds_swizzle(x, 0x081F));
    x = __float_as_int(e);
    e += __int_as_float(__builtin_amdgcn_ds_swizzle(x, 0x101F));
    return e;
}

// ---------------- K1: W split (blocks 0..255) + hist/rank (rest) ----------------
__global__ __launch_bounds__(256) void k_prep(
        const float* __restrict__ Wq, const float* __restrict__ Wk,
        const float* __restrict__ Wv, const float* __restrict__ Wp,
        __bf16* __restrict__ wsplit, const int* __restrict__ qidx,
        int* __restrict__ counts, int* __restrict__ rank, int E) {
    int bi = blockIdx.x;
    if (bi < 256) {
        int w = bi >> 6;
        const float* W = (w == 0) ? Wq : (w == 1) ? Wk : (w == 2) ? Wv : Wp;
        __bf16* hi = wsplit + (size_t)w * 32768;
        __bf16* lo = hi + 16384;
        int i = (bi & 63) * 256 + threadIdx.x;
        float x = W[i];
        __bf16 h = (__bf16)x;
        hi[i] = h;
        lo[i] = (__bf16)(x - (float)h);
    } else {
        int i = (bi - 256) * 256 + threadIdx.x;
        if (i < E) rank[i] = atomicAdd(&counts[qidx[i]], 1);
    }
}

// ---------------- K2: persistent-grid projections (+ scan1 in low blocks) -----
// W fragments live in registers (Bf = 128 VGPR). __launch_bounds__(256,1)
// lifts the VGPR cap to 512 so Bf does NOT spill to scratch (R4: VGPR=112
// meant Bf lived in scratch -> all pipes idle). ~2 waves/SIMD resident.
__global__ __launch_bounds__(256, 1) void k_proj2(
        const float* __restrict__ query, const float* __restrict__ keys,
        const float* __restrict__ values, const __bf16* __restrict__ wsplit,
        const float* __restrict__ bq, const float* __restrict__ bk,
        const float* __restrict__ bv, float* __restrict__ Qp,
        __bf16* __restrict__ KV, int NQ_, int NK_,
        const int* __restrict__ counts, int* __restrict__ offs,
        int* __restrict__ bsum, int nb) {
    __shared__ int s[256];
    // ---- scan1 piggyback (counts ready: k_prep ran before) ----
    if ((int)blockIdx.x < nb) {
        int t = threadIdx.x;
        int i = blockIdx.x * 256 + t;
        int v = (i < NQ_) ? counts[i] : 0;
        s[t] = v;
        __syncthreads();
        for (int o = 1; o < 256; o <<= 1) {
            int x = (t >= o) ? s[t - o] : 0;
            __syncthreads();
            s[t] += x;
            __syncthreads();
        }
        if (i < NQ_) offs[i] = s[t] - v;
        if (t == 255) bsum[blockIdx.x] = s[t];
    }

    int lane = threadIdx.x & 63;
    int wid  = threadIdx.x >> 6;
    int r = lane & 15, g = lane >> 4;
    int rowoff = (wid >> 1) * 16;   // 0 or 16 within the 32-row tile
    int chalf  = wid & 1;           // column half: cols [chalf*64, chalf*64+64)

    int ntq = (NQ_ + 31) >> 5;
    int ntk = (NK_ + 31) >> 5;
    int total = ntq + 2 * ntk;

    int mode = -1;
    bf16x8 Bf[4][4][2];             // [ct][ks][hi/lo] -- 128 VGPR, persistent
    float  bias_n[4];

    for (int t = blockIdx.x; t < total; t += gridDim.x) {
        int m, tt;
        if (t < ntq)            { m = 0; tt = t; }
        else if (t < ntq + ntk) { m = 1; tt = t - ntq; }
        else                    { m = 2; tt = t - ntq - ntk; }

        if (m != mode) {
            mode = m;
            const __bf16* wh = wsplit + (size_t)m * 32768;
            const __bf16* wl = wh + 16384;
            const float* bias = (m == 0) ? bq : (m == 1) ? bk : bv;
#pragma unroll
            for (int c = 0; c < 4; ++c) {
                int n = (chalf * 4 + c) * 16 + r;
#pragma unroll
                for (int ks = 0; ks < 4; ++ks) {
                    Bf[c][ks][0] = *(const bf16x8*)(wh + n * DIMN + ks * 32 + g * 8);
                    Bf[c][ks][1] = *(const bf16x8*)(wl + n * DIMN + ks * 32 + g * 8);
                }
                bias_n[c] = bias[n];
            }
        }

        const float* X = (m == 0) ? query : (m == 1) ? keys : values;
        int M = (m == 0) ? NQ_ : NK_;
        int rb = tt * 32 + rowoff;
        int arow = rb + r; if (arow >= M) arow = M - 1;
        const float* xrow = X + (size_t)arow * DIMN;

        bf16x8 Ah[4], Al[4];
#pragma unroll
        for (int ks = 0; ks < 4; ++ks) {
            const float* px = xrow + ks * 32 + g * 8;
            f32x4 v0 = *(const f32x4*)(px);
            f32x4 v1 = *(const f32x4*)(px + 4);
#pragma unroll
            for (int i = 0; i < 4; ++i) {
                __bf16 h0 = (__bf16)v0[i];
                __bf16 h1 = (__bf16)v1[i];
                Ah[ks][i]     = h0;
                Ah[ks][i + 4] = h1;
                Al[ks][i]     = (__bf16)(v0[i] - (float)h0);
                Al[ks][i + 4] = (__bf16)(v1[i] - (float)h1);
            }
        }

        f32x4 acc[4];
#pragma unroll
        for (int c = 0; c < 4; ++c) {
            acc[c] = (f32x4){0.f, 0.f, 0.f, 0.f};
#pragma unroll
            for (int ks = 0; ks < 4; ++ks) {
                acc[c] = __builtin_amdgcn_mfma_f32_16x16x32_bf16(Ah[ks], Bf[c][ks][0], acc[c], 0, 0, 0);
                acc[c] = __builtin_amdgcn_mfma_f32_16x16x32_bf16(Ah[ks], Bf[c][ks][1], acc[c], 0, 0, 0);
                acc[c] = __builtin_amdgcn_mfma_f32_16x16x32_bf16(Al[ks], Bf[c][ks][0], acc[c], 0, 0, 0);
            }
        }

        if (m == 0) {
#pragma unroll
            for (int c = 0; c < 4; ++c) {
                int n = (chalf * 4 + c) * 16 + r;
#pragma unroll
                for (int i = 0; i < 4; ++i) {
                    int row = rb + g * 4 + i;
                    if (row < M) Qp[(size_t)row * DIMN + n] = acc[c][i] + bias_n[c];
                }
            }
        } else {
            int vofs = (m == 2) ? 128 : 0;
#pragma unroll
            for (int c = 0; c < 4; ++c) {
                int n = (chalf * 4 + c) * 16 + r;
#pragma unroll
                for (int i = 0; i < 4; ++i) {
                    int row = rb + g * 4 + i;
                    if (row < M) KV[(size_t)row * 256 + vofs + n] = (__bf16)(acc[c][i] + bias_n[c]);
                }
            }
        }
    }
}

__global__ __launch_bounds__(1024) void k_scan2(int* __restrict__ bsum, int nb) {
    __shared__ int s[1024];
    int t = threadIdx.x;
    int v = (t < nb) ? bsum[t] : 0;
    s[t] = v;
    __syncthreads();
    for (int o = 1; o < 1024; o <<= 1) {
        int x = (t >= o) ? s[t - o] : 0;
        __syncthreads();
        s[t] += x;
        __syncthreads();
    }
    if (t < nb) bsum[t] = s[t];  // inclusive block-sum scan
}

// final offset of query i = offs[i] + (i>=256 ? bsum[i/256-1] : 0)
__global__ void k_scatter(const int* __restrict__ qidx, const int* __restrict__ kidx,
                          const int* __restrict__ offs, const int* __restrict__ bsum,
                          const int* __restrict__ rank, int* __restrict__ skey, int E) {
    int i = blockIdx.x * 256 + threadIdx.x;
    if (i < E) {
        int q = qidx[i];
        int base = offs[q] + ((q >= 256) ? bsum[(q >> 8) - 1] : 0);
        skey[base + rank[i]] = kidx[i];
    }
}

// ---------------- per-query softmax aggregation (1 wave / query) ----------------
__global__ __launch_bounds__(256) void k_attn(
        const float* __restrict__ Qp, const __bf16* __restrict__ KV,
        const int* __restrict__ offs, const int* __restrict__ bsum,
        const int* __restrict__ skey, const float* __restrict__ a,
        const float* __restrict__ prelu_w, float* __restrict__ msg,
        int NQ_, int E_) {
    int lane = threadIdx.x & 63;
    int q = blockIdx.x * 4 + (threadIdx.x >> 6);
    if (q >= NQ_) return;
    int d = lane * 2;
    float2 av = *(const float2*)(a + d);
    float a0 = av.x, a1 = av.y;
    float pw = prelu_w[0];
    float2 qv = *(const float2*)(Qp + (size_t)q * DIMN + d);
    float q0 = qv.x, q1 = qv.y;
    int beg = offs[q] + ((q >= 256) ? bsum[(q >> 8) - 1] : 0);
    int qn = q + 1;
    int end = (qn == NQ_) ? E_ : offs[qn] + ((qn >= 256) ? bsum[(qn >> 8) - 1] : 0);

    float den = 0.f, acc0 = 0.f, acc1 = 0.f;
    int j = beg;
    for (; j + 3 < end; j += 4) {
        int k0 = skey[j], k1 = skey[j + 1], k2 = skey[j + 2], k3 = skey[j + 3];
        const uint32_t* r0 = (const uint32_t*)(KV + ((size_t)k0 << 8));
        const uint32_t* r1 = (const uint32_t*)(KV + ((size_t)k1 << 8));
        const uint32_t* r2 = (const uint32_t*)(KV + ((size_t)k2 << 8));
        const uint32_t* r3 = (const uint32_t*)(KV + ((size_t)k3 << 8));
        uint32_t ku0 = r0[lane], ku1 = r1[lane], ku2 = r2[lane], ku3 = r3[lane];
        uint32_t vu0 = r0[64 + lane], vu1 = r1[64 + lane], vu2 = r2[64 + lane], vu3 = r3[64 + lane];

        float e0, e1, e2, e3;
        {
            float s0 = q0 + bf_even(ku0), s1 = q1 + bf_odd(ku0);
            s0 = s0 >= 0.f ? s0 : pw * s0;  s1 = s1 >= 0.f ? s1 : pw * s1;
            e0 = a0 * s0 + a1 * s1;
        }
        {
            float s0 = q0 + bf_even(ku1), s1 = q1 + bf_odd(ku1);
            s0 = s0 >= 0.f ? s0 : pw * s0;  s1 = s1 >= 0.f ? s1 : pw * s1;
            e1 = a0 * s0 + a1 * s1;
        }
        {
            float s0 = q0 + bf_even(ku2), s1 = q1 + bf_odd(ku2);
            s0 = s0 >= 0.f ? s0 : pw * s0;  s1 = s1 >= 0.f ? s1 : pw * s1;
            e2 = a0 * s0 + a1 * s1;
        }
        {
            float s0 = q0 + bf_even(ku3), s1 = q1 + bf_odd(ku3);
            s0 = s0 >= 0.f ? s0 : pw * s0;  s1 = s1 >= 0.f ? s1 : pw * s1;
            e3 = a0 * s0 + a1 * s1;
        }
        e0 = head_reduce(e0);
        e1 = head_reduce(e1);
        e2 = head_reduce(e2);
        e3 = head_reduce(e3);
        float w0 = __expf(e0), w1 = __expf(e1), w2 = __expf(e2), w3 = __expf(e3);
        den  += (w0 + w1) + (w2 + w3);
        acc0 += w0 * bf_even(vu0) + w1 * bf_even(vu1) + w2 * bf_even(vu2) + w3 * bf_even(vu3);
        acc1 += w0 * bf_odd(vu0)  + w1 * bf_odd(vu1)  + w2 * bf_odd(vu2)  + w3 * bf_odd(vu3);
    }
    for (; j < end; ++j) {
        int k = skey[j];
        const uint32_t* r_ = (const uint32_t*)(KV + ((size_t)k << 8));
        uint32_t ku = r_[lane], vu = r_[64 + lane];
        float s0 = q0 + bf_even(ku), s1 = q1 + bf_odd(ku);
        s0 = s0 >= 0.f ? s0 : pw * s0;  s1 = s1 >= 0.f ? s1 : pw * s1;
        float e = a0 * s0 + a1 * s1;
        e = head_reduce(e);
        float w = __expf(e);
        den += w;
        acc0 += w * bf_even(vu);
        acc1 += w * bf_odd(vu);
    }
    float inv = den > 0.f ? 1.f / den : 0.f;
    float2 o; o.x = acc0 * inv; o.y = acc1 * inv;
    *(float2*)(msg + (size_t)q * DIMN + d) = o;   // msg aliases Qp (row q only)
}

// ---------------- final: x = query + msg@Wp^T + bp; LayerNorm ----------------
__global__ __launch_bounds__(256) void k_final(
        const float* __restrict__ msg, const __bf16* __restrict__ wh,
        const __bf16* __restrict__ wl, const float* __restrict__ bp,
        const float* __restrict__ query, const float* __restrict__ lng,
        const float* __restrict__ lnb, float* __restrict__ out, int M) {
    int lane = threadIdx.x & 63;
    int wid  = threadIdx.x >> 6;
    int r = lane & 15, g = lane >> 4;
    int rb = blockIdx.x * 64 + wid * 16;

    int arow = rb + r; if (arow >= M) arow = M - 1;
    const float* xrow = msg + (size_t)arow * DIMN;
    bf16x8 Ah[4], Al[4];
#pragma unroll
    for (int ks = 0; ks < 4; ++ks) {
        const float* px = xrow + ks * 32 + g * 8;
#pragma unroll
        for (int i = 0; i < 8; ++i) {
            float v = px[i];
            __bf16 h = (__bf16)v;
            Ah[ks][i] = h;
            Al[ks][i] = (__bf16)(v - (float)h);
        }
    }
    float xv[8][4];
#pragma unroll
    for (int ct = 0; ct < 8; ++ct) {
        f32x4 acc = {0.f, 0.f, 0.f, 0.f};
        int n = ct * 16 + r;
        const __bf16* bh = wh + n * DIMN + g * 8;
        const __bf16* bl = wl + n * DIMN + g * 8;
#pragma unroll
        for (int ks = 0; ks < 4; ++ks) {
            bf16x8 Bh = *(const bf16x8*)(bh + ks * 32);
            bf16x8 Bl = *(const bf16x8*)(bl + ks * 32);
            acc = __builtin_amdgcn_mfma_f32_16x16x32_bf16(Ah[ks], Bh, acc, 0, 0, 0);
            acc = __builtin_amdgcn_mfma_f32_16x16x32_bf16(Ah[ks], Bl, acc, 0, 0, 0);
            acc = __builtin_amdgcn_mfma_f32_16x16x32_bf16(Al[ks], Bh, acc, 0, 0, 0);
        }
        float bn = bp[n];
#pragma unroll
        for (int i = 0; i < 4; ++i) {
            int row = rb + g * 4 + i;
            int rc = row < M ? row : M - 1;
            xv[ct][i] = acc[i] + bn + query[(size_t)rc * DIMN + n];
        }
    }
#pragma unroll
    for (int i = 0; i < 4; ++i) {
        float s = 0.f, ss = 0.f;
#pragma unroll
        for (int ct = 0; ct < 8; ++ct) { s += xv[ct][i]; ss += xv[ct][i] * xv[ct][i]; }
        s += __shfl_xor(s, 1, 64);  ss += __shfl_xor(ss, 1, 64);
        s += __shfl_xor(s, 2, 64);  ss += __shfl_xor(ss, 2, 64);
        s += __shfl_xor(s, 4, 64);  ss += __shfl_xor(ss, 4, 64);
        s += __shfl_xor(s, 8, 64);  ss += __shfl_xor(ss, 8, 64);
        float mean = s * (1.f / DIMN);
        float var  = ss * (1.f / DIMN) - mean * mean;
        float rstd = rsqrtf(var + LN_EPS);
        int row = rb + g * 4 + i;
#pragma unroll
        for (int ct = 0; ct < 8; ++ct) {
            int n = ct * 16 + r;
            if (row < M)
                out[(size_t)row * DIMN + n] = (xv[ct][i] - mean) * rstd * lng[n] + lnb[n];
        }
    }
}

extern "C" void kernel_launch(void* const* d_in, const int* in_sizes, int n_in,
                              void* d_out, int out_size, void* d_ws, size_t ws_size,
                              hipStream_t stream) {
    const float* query = (const float*)d_in[0];
    const float* keys  = (const float*)d_in[1];
    const float* values= (const float*)d_in[2];
    const int*   qidx  = (const int*)d_in[3];
    const int*   kidx  = (const int*)d_in[4];
    const float* Wq    = (const float*)d_in[5];
    const float* bq    = (const float*)d_in[6];
    const float* Wk    = (const float*)d_in[7];
    const float* bk    = (const float*)d_in[8];
    const float* Wv    = (const float*)d_in[9];
    const float* bv    = (const float*)d_in[10];
    const float* Wp    = (const float*)d_in[11];
    const float* bp    = (const float*)d_in[12];
    const float* a     = (const float*)d_in[13];
    const float* pw    = (const float*)d_in[14];
    const float* lng   = (const float*)d_in[15];
    const float* lnb   = (const float*)d_in[16];

    int NQ_ = in_sizes[0] / DIMN;
    int NK_ = in_sizes[1] / DIMN;
    int E_  = in_sizes[3];

    char* p = (char*)d_ws;
    __bf16* wsplit = (__bf16*)p;
    size_t off = (size_t)4 * 32768 * sizeof(__bf16);
    float*  Qp = (float*)(p + off);  off += (size_t)NQ_ * DIMN * 4;
    __bf16* KV = (__bf16*)(p + off); off += (size_t)NK_ * 256 * 2;
    int* counts = (int*)(p + off); off += (((size_t)NQ_ * 4) + 127) / 128 * 128;
    int* offs   = (int*)(p + off); off += (((size_t)NQ_ * 4) + 127) / 128 * 128;
    int* bsum   = (int*)(p + off); off += 1024 * 4;
    int* rank   = (int*)(p + off); off += (size_t)E_ * 4;
    int* skey   = (int*)(p + off); off += (size_t)E_ * 4;
    float* msg  = Qp;  // aliasing is safe: wave for query q reads only Qp row q

    hipMemsetAsync(counts, 0, (size_t)NQ_ * 4, stream);

    int ge = (E_ + 255) / 256;
    int gm = (NQ_ + 63) / 64;
    int nb = (NQ_ + 255) / 256;

    k_prep<<<256 + ge, 256, 0, stream>>>(Wq, Wk, Wv, Wp, wsplit, qidx, counts, rank, E_);

    k_proj2<<<2048, 256, 0, stream>>>(query, keys, values, wsplit, bq, bk, bv,
                                      Qp, KV, NQ_, NK_, counts, offs, bsum, nb);

    k_scan2<<<1, 1024, 0, stream>>>(bsum, nb);

    k_scatter<<<ge, 256, 0, stream>>>(qidx, kidx, offs, bsum, rank, skey, E_);

    k_attn<<<(NQ_ + 3) / 4, 256, 0, stream>>>(Qp, KV, offs, bsum, skey, a, pw, msg, NQ_, E_);

    k_final<<<gm, 256, 0, stream>>>(msg, wsplit + 3 * 32768, wsplit + 3 * 32768 + 16384,
                                    bp, query, lng, lnb, (float*)d_out, NQ_);
}

// Round 6
// 363.629 us; speedup vs baseline: 2.2946x; 1.1982x over previous
//
#include <hip/hip_runtime.h>
#include <hip/hip_bf16.h>

#define DIMN 128
#define LN_EPS 1e-5f
#define WPAD 136   // padded row length in bf16 (272 B = 17*16, keeps b128 aligned, ~2-way banks)

typedef __bf16 bf16x8 __attribute__((ext_vector_type(8)));
typedef float f32x4 __attribute__((ext_vector_type(4)));

__device__ __forceinline__ float bf_even(uint32_t u) {  // element at even dim (low 16 bits)
    union { uint32_t u; float f; } c; c.u = u << 16; return c.f;
}
__device__ __forceinline__ float bf_odd(uint32_t u) {   // element at odd dim (high 16 bits)
    union { uint32_t u; float f; } c; c.u = u & 0xffff0000u; return c.f;
}

// 8-lane xor-reduction via ds_swizzle (no address VALU, 1 LDS-pipe op each).
__device__ __forceinline__ float head_reduce(float e) {
    int x = __float_as_int(e);
    e += __int_as_float(__builtin_amdgcn_ds_swizzle(x, 0x041F));
    x = __float_as_int(e);
    e += __int_as_float(__builtin_amdgcn_ds_swizzle(x, 0x081F));
    x = __float_as_int(e);
    e += __int_as_float(__builtin_amdgcn_ds_swizzle(x, 0x101F));
    return e;
}

// ---------------- K1: W split (blocks 0..255) + hist/rank (rest) ----------------
__global__ __launch_bounds__(256) void k_prep(
        const float* __restrict__ Wq, const float* __restrict__ Wk,
        const float* __restrict__ Wv, const float* __restrict__ Wp,
        __bf16* __restrict__ wsplit, const int* __restrict__ qidx,
        int* __restrict__ counts, int* __restrict__ rank, int E) {
    int bi = blockIdx.x;
    if (bi < 256) {
        int w = bi >> 6;
        const float* W = (w == 0) ? Wq : (w == 1) ? Wk : (w == 2) ? Wv : Wp;
        __bf16* hi = wsplit + (size_t)w * 32768;
        __bf16* lo = hi + 16384;
        int i = (bi & 63) * 256 + threadIdx.x;
        float x = W[i];
        __bf16 h = (__bf16)x;
        hi[i] = h;
        lo[i] = (__bf16)(x - (float)h);
    } else {
        int i = (bi - 256) * 256 + threadIdx.x;
        if (i < E) rank[i] = atomicAdd(&counts[qidx[i]], 1);
    }
}

// ---------------- K2: LDS-W projections (+ scan1 in low blocks) ----------------
// W (hi+lo) staged in LDS once per block; chunked contiguous tile ranges so a
// block re-stages at most once (mode boundary). Q: 3-pass bf16-split MFMA.
// K/V: single-pass bf16 (outputs are rounded to bf16 anyway; 1-pass GEMM error
// ~0.0016 < storage rounding ~0.004).
__global__ __launch_bounds__(256, 2) void k_proj3(
        const float* __restrict__ query, const float* __restrict__ keys,
        const float* __restrict__ values, const __bf16* __restrict__ wsplit,
        const float* __restrict__ bq, const float* __restrict__ bk,
        const float* __restrict__ bv, float* __restrict__ Qp,
        __bf16* __restrict__ KV, int NQ_, int NK_,
        const int* __restrict__ counts, int* __restrict__ offs,
        int* __restrict__ bsum, int nb, int chunk) {
    __shared__ int s[256];
    __shared__ __align__(16) __bf16 WH[128 * WPAD];
    __shared__ __align__(16) __bf16 WL[128 * WPAD];

    // ---- scan1 piggyback (counts ready: k_prep ran before) ----
    if ((int)blockIdx.x < nb) {
        int t = threadIdx.x;
        int i = blockIdx.x * 256 + t;
        int v = (i < NQ_) ? counts[i] : 0;
        s[t] = v;
        __syncthreads();
        for (int o = 1; o < 256; o <<= 1) {
            int x = (t >= o) ? s[t - o] : 0;
            __syncthreads();
            s[t] += x;
            __syncthreads();
        }
        if (i < NQ_) offs[i] = s[t] - v;
        if (t == 255) bsum[blockIdx.x] = s[t];
    }

    int lane = threadIdx.x & 63;
    int wid  = threadIdx.x >> 6;
    int r = lane & 15, g = lane >> 4;
    int rowoff = (wid >> 1) * 16;   // 0 or 16 within the 32-row tile
    int chalf  = wid & 1;           // column half: cols [chalf*64, chalf*64+64)

    int ntq = (NQ_ + 31) >> 5;
    int ntk = (NK_ + 31) >> 5;
    int total = ntq + 2 * ntk;

    int t0 = blockIdx.x * chunk;
    int t1 = t0 + chunk; if (t1 > total) t1 = total;
    int staged = -1;
    float bias_n[4];

    for (int t = t0; t < t1; ++t) {
        int m, tt;
        if (t < ntq)            { m = 0; tt = t; }
        else if (t < ntq + ntk) { m = 1; tt = t - ntq; }
        else                    { m = 2; tt = t - ntq - ntk; }

        if (m != staged) {
            if (staged != -1) __syncthreads();   // drain readers of old W
            const uint4* srcH = (const uint4*)(wsplit + (size_t)m * 32768);
            const uint4* srcL = (const uint4*)(wsplit + (size_t)m * 32768 + 16384);
#pragma unroll
            for (int it = 0; it < 8; ++it) {
                int cid = threadIdx.x + it * 256;     // 2048 16B-chunks per plane
                int n = cid >> 4, c16 = cid & 15;
                *(uint4*)((char*)WH + n * (WPAD * 2) + c16 * 16) = srcH[cid];
                *(uint4*)((char*)WL + n * (WPAD * 2) + c16 * 16) = srcL[cid];
            }
            __syncthreads();
            staged = m;
            const float* bias = (m == 0) ? bq : (m == 1) ? bk : bv;
#pragma unroll
            for (int c = 0; c < 4; ++c) bias_n[c] = bias[(chalf * 4 + c) * 16 + r];
        }

        const float* X = (m == 0) ? query : (m == 1) ? keys : values;
        int M = (m == 0) ? NQ_ : NK_;
        int rb = tt * 32 + rowoff;
        int arow = rb + r; if (arow >= M) arow = M - 1;
        const float* xrow = X + (size_t)arow * DIMN;

        bf16x8 Ah[4], Al[4];
#pragma unroll
        for (int ks = 0; ks < 4; ++ks) {
            const float* px = xrow + ks * 32 + g * 8;
            f32x4 v0 = *(const f32x4*)(px);
            f32x4 v1 = *(const f32x4*)(px + 4);
#pragma unroll
            for (int i = 0; i < 4; ++i) {
                __bf16 h0 = (__bf16)v0[i];
                __bf16 h1 = (__bf16)v1[i];
                Ah[ks][i]     = h0;
                Ah[ks][i + 4] = h1;
                if (m == 0) {
                    Al[ks][i]     = (__bf16)(v0[i] - (float)h0);
                    Al[ks][i + 4] = (__bf16)(v1[i] - (float)h1);
                }
            }
        }

        f32x4 acc[4];
#pragma unroll
        for (int c = 0; c < 4; ++c) {
            acc[c] = (f32x4){0.f, 0.f, 0.f, 0.f};
            int n = (chalf * 4 + c) * 16 + r;
#pragma unroll
            for (int ks = 0; ks < 4; ++ks) {
                bf16x8 Bh = *(const bf16x8*)(WH + n * WPAD + ks * 32 + g * 8);
                acc[c] = __builtin_amdgcn_mfma_f32_16x16x32_bf16(Ah[ks], Bh, acc[c], 0, 0, 0);
                if (m == 0) {
                    bf16x8 Bl = *(const bf16x8*)(WL + n * WPAD + ks * 32 + g * 8);
                    acc[c] = __builtin_amdgcn_mfma_f32_16x16x32_bf16(Ah[ks], Bl, acc[c], 0, 0, 0);
                    acc[c] = __builtin_amdgcn_mfma_f32_16x16x32_bf16(Al[ks], Bh, acc[c], 0, 0, 0);
                }
            }
        }

        if (m == 0) {
#pragma unroll
            for (int c = 0; c < 4; ++c) {
                int n = (chalf * 4 + c) * 16 + r;
#pragma unroll
                for (int i = 0; i < 4; ++i) {
                    int row = rb + g * 4 + i;
                    if (row < M) Qp[(size_t)row * DIMN + n] = acc[c][i] + bias_n[c];
                }
            }
        } else {
            int vofs = (m == 2) ? 128 : 0;
#pragma unroll
            for (int c = 0; c < 4; ++c) {
                int n = (chalf * 4 + c) * 16 + r;
#pragma unroll
                for (int i = 0; i < 4; ++i) {
                    int row = rb + g * 4 + i;
                    if (row < M) KV[(size_t)row * 256 + vofs + n] = (__bf16)(acc[c][i] + bias_n[c]);
                }
            }
        }
    }
}

__global__ __launch_bounds__(1024) void k_scan2(int* __restrict__ bsum, int nb) {
    __shared__ int s[1024];
    int t = threadIdx.x;
    int v = (t < nb) ? bsum[t] : 0;
    s[t] = v;
    __syncthreads();
    for (int o = 1; o < 1024; o <<= 1) {
        int x = (t >= o) ? s[t - o] : 0;
        __syncthreads();
        s[t] += x;
        __syncthreads();
    }
    if (t < nb) bsum[t] = s[t];  // inclusive block-sum scan
}

// final offset of query i = offs[i] + (i>=256 ? bsum[i/256-1] : 0)
__global__ void k_scatter(const int* __restrict__ qidx, const int* __restrict__ kidx,
                          const int* __restrict__ offs, const int* __restrict__ bsum,
                          const int* __restrict__ rank, int* __restrict__ skey, int E) {
    int i = blockIdx.x * 256 + threadIdx.x;
    if (i < E) {
        int q = qidx[i];
        int base = offs[q] + ((q >= 256) ? bsum[(q >> 8) - 1] : 0);
        skey[base + rank[i]] = kidx[i];
    }
}

// ---------------- per-query softmax aggregation (1 wave / query) ----------------
__global__ __launch_bounds__(256) void k_attn(
        const float* __restrict__ Qp, const __bf16* __restrict__ KV,
        const int* __restrict__ offs, const int* __restrict__ bsum,
        const int* __restrict__ skey, const float* __restrict__ a,
        const float* __restrict__ prelu_w, float* __restrict__ msg,
        int NQ_, int E_) {
    int lane = threadIdx.x & 63;
    int q = blockIdx.x * 4 + (threadIdx.x >> 6);
    if (q >= NQ_) return;
    int d = lane * 2;
    float2 av = *(const float2*)(a + d);
    float a0 = av.x, a1 = av.y;
    float pw = prelu_w[0];
    float2 qv = *(const float2*)(Qp + (size_t)q * DIMN + d);
    float q0 = qv.x, q1 = qv.y;
    int beg = offs[q] + ((q >= 256) ? bsum[(q >> 8) - 1] : 0);
    int qn = q + 1;
    int end = (qn == NQ_) ? E_ : offs[qn] + ((qn >= 256) ? bsum[(qn >> 8) - 1] : 0);

    float den = 0.f, acc0 = 0.f, acc1 = 0.f;
    int j = beg;
    for (; j + 3 < end; j += 4) {
        int k0 = skey[j], k1 = skey[j + 1], k2 = skey[j + 2], k3 = skey[j + 3];
        const uint32_t* r0 = (const uint32_t*)(KV + ((size_t)k0 << 8));
        const uint32_t* r1 = (const uint32_t*)(KV + ((size_t)k1 << 8));
        const uint32_t* r2 = (const uint32_t*)(KV + ((size_t)k2 << 8));
        const uint32_t* r3 = (const uint32_t*)(KV + ((size_t)k3 << 8));
        uint32_t ku0 = r0[lane], ku1 = r1[lane], ku2 = r2[lane], ku3 = r3[lane];
        uint32_t vu0 = r0[64 + lane], vu1 = r1[64 + lane], vu2 = r2[64 + lane], vu3 = r3[64 + lane];

        float e0, e1, e2, e3;
        {
            float s0 = q0 + bf_even(ku0), s1 = q1 + bf_odd(ku0);
            s0 = s0 >= 0.f ? s0 : pw * s0;  s1 = s1 >= 0.f ? s1 : pw * s1;
            e0 = a0 * s0 + a1 * s1;
        }
        {
            float s0 = q0 + bf_even(ku1), s1 = q1 + bf_odd(ku1);
            s0 = s0 >= 0.f ? s0 : pw * s0;  s1 = s1 >= 0.f ? s1 : pw * s1;
            e1 = a0 * s0 + a1 * s1;
        }
        {
            float s0 = q0 + bf_even(ku2), s1 = q1 + bf_odd(ku2);
            s0 = s0 >= 0.f ? s0 : pw * s0;  s1 = s1 >= 0.f ? s1 : pw * s1;
            e2 = a0 * s0 + a1 * s1;
        }
        {
            float s0 = q0 + bf_even(ku3), s1 = q1 + bf_odd(ku3);
            s0 = s0 >= 0.f ? s0 : pw * s0;  s1 = s1 >= 0.f ? s1 : pw * s1;
            e3 = a0 * s0 + a1 * s1;
        }
        e0 = head_reduce(e0);
        e1 = head_reduce(e1);
        e2 = head_reduce(e2);
        e3 = head_reduce(e3);
        float w0 = __expf(e0), w1 = __expf(e1), w2 = __expf(e2), w3 = __expf(e3);
        den  += (w0 + w1) + (w2 + w3);
        acc0 += w0 * bf_even(vu0) + w1 * bf_even(vu1) + w2 * bf_even(vu2) + w3 * bf_even(vu3);
        acc1 += w0 * bf_odd(vu0)  + w1 * bf_odd(vu1)  + w2 * bf_odd(vu2)  + w3 * bf_odd(vu3);
    }
    for (; j < end; ++j) {
        int k = skey[j];
        const uint32_t* r_ = (const uint32_t*)(KV + ((size_t)k << 8));
        uint32_t ku = r_[lane], vu = r_[64 + lane];
        float s0 = q0 + bf_even(ku), s1 = q1 + bf_odd(ku);
        s0 = s0 >= 0.f ? s0 : pw * s0;  s1 = s1 >= 0.f ? s1 : pw * s1;
        float e = a0 * s0 + a1 * s1;
        e = head_reduce(e);
        float w = __expf(e);
        den += w;
        acc0 += w * bf_even(vu);
        acc1 += w * bf_odd(vu);
    }
    float inv = den > 0.f ? 1.f / den : 0.f;
    float2 o; o.x = acc0 * inv; o.y = acc1 * inv;
    *(float2*)(msg + (size_t)q * DIMN + d) = o;   // msg aliases Qp (row q only)
}

// ---------------- final: x = query + msg@Wp^T + bp; LayerNorm ----------------
__global__ __launch_bounds__(256, 2) void k_final(
        const float* __restrict__ msg, const __bf16* __restrict__ wh,
        const __bf16* __restrict__ wl, const float* __restrict__ bp,
        const float* __restrict__ query, const float* __restrict__ lng,
        const float* __restrict__ lnb, float* __restrict__ out, int M) {
    __shared__ __align__(16) __bf16 WH[128 * WPAD];
    __shared__ __align__(16) __bf16 WL[128 * WPAD];
    {
        const uint4* srcH = (const uint4*)wh;
        const uint4* srcL = (const uint4*)wl;
#pragma unroll
        for (int it = 0; it < 8; ++it) {
            int cid = threadIdx.x + it * 256;
            int n = cid >> 4, c16 = cid & 15;
            *(uint4*)((char*)WH + n * (WPAD * 2) + c16 * 16) = srcH[cid];
            *(uint4*)((char*)WL + n * (WPAD * 2) + c16 * 16) = srcL[cid];
        }
    }
    __syncthreads();

    int lane = threadIdx.x & 63;
    int wid  = threadIdx.x >> 6;
    int r = lane & 15, g = lane >> 4;
    int rb = blockIdx.x * 64 + wid * 16;

    int arow = rb + r; if (arow >= M) arow = M - 1;
    const float* xrow = msg + (size_t)arow * DIMN;
    bf16x8 Ah[4], Al[4];
#pragma unroll
    for (int ks = 0; ks < 4; ++ks) {
        const float* px = xrow + ks * 32 + g * 8;
        f32x4 v0 = *(const f32x4*)(px);
        f32x4 v1 = *(const f32x4*)(px + 4);
#pragma unroll
        for (int i = 0; i < 4; ++i) {
            __bf16 h0 = (__bf16)v0[i];
            __bf16 h1 = (__bf16)v1[i];
            Ah[ks][i]     = h0;
            Ah[ks][i + 4] = h1;
            Al[ks][i]     = (__bf16)(v0[i] - (float)h0);
            Al[ks][i + 4] = (__bf16)(v1[i] - (float)h1);
        }
    }
    float xv[8][4];
#pragma unroll
    for (int ct = 0; ct < 8; ++ct) {
        f32x4 acc = {0.f, 0.f, 0.f, 0.f};
        int n = ct * 16 + r;
#pragma unroll
        for (int ks = 0; ks < 4; ++ks) {
            bf16x8 Bh = *(const bf16x8*)(WH + n * WPAD + ks * 32 + g * 8);
            bf16x8 Bl = *(const bf16x8*)(WL + n * WPAD + ks * 32 + g * 8);
            acc = __builtin_amdgcn_mfma_f32_16x16x32_bf16(Ah[ks], Bh, acc, 0, 0, 0);
            acc = __builtin_amdgcn_mfma_f32_16x16x32_bf16(Ah[ks], Bl, acc, 0, 0, 0);
            acc = __builtin_amdgcn_mfma_f32_16x16x32_bf16(Al[ks], Bh, acc, 0, 0, 0);
        }
        float bn = bp[n];
#pragma unroll
        for (int i = 0; i < 4; ++i) {
            int row = rb + g * 4 + i;
            int rc = row < M ? row : M - 1;
            xv[ct][i] = acc[i] + bn + query[(size_t)rc * DIMN + n];
        }
    }
#pragma unroll
    for (int i = 0; i < 4; ++i) {
        float s = 0.f, ss = 0.f;
#pragma unroll
        for (int ct = 0; ct < 8; ++ct) { s += xv[ct][i]; ss += xv[ct][i] * xv[ct][i]; }
        s += __shfl_xor(s, 1, 64);  ss += __shfl_xor(ss, 1, 64);
        s += __shfl_xor(s, 2, 64);  ss += __shfl_xor(ss, 2, 64);
        s += __shfl_xor(s, 4, 64);  ss += __shfl_xor(ss, 4, 64);
        s += __shfl_xor(s, 8, 64);  ss += __shfl_xor(ss, 8, 64);
        float mean = s * (1.f / DIMN);
        float var  = ss * (1.f / DIMN) - mean * mean;
        float rstd = rsqrtf(var + LN_EPS);
        int row = rb + g * 4 + i;
#pragma unroll
        for (int ct = 0; ct < 8; ++ct) {
            int n = ct * 16 + r;
            if (row < M)
                out[(size_t)row * DIMN + n] = (xv[ct][i] - mean) * rstd * lng[n] + lnb[n];
        }
    }
}

extern "C" void kernel_launch(void* const* d_in, const int* in_sizes, int n_in,
                              void* d_out, int out_size, void* d_ws, size_t ws_size,
                              hipStream_t stream) {
    const float* query = (const float*)d_in[0];
    const float* keys  = (const float*)d_in[1];
    const float* values= (const float*)d_in[2];
    const int*   qidx  = (const int*)d_in[3];
    const int*   kidx  = (const int*)d_in[4];
    const float* Wq    = (const float*)d_in[5];
    const float* bq    = (const float*)d_in[6];
    const float* Wk    = (const float*)d_in[7];
    const float* bk    = (const float*)d_in[8];
    const float* Wv    = (const float*)d_in[9];
    const float* bv    = (const float*)d_in[10];
    const float* Wp    = (const float*)d_in[11];
    const float* bp    = (const float*)d_in[12];
    const float* a     = (const float*)d_in[13];
    const float* pw    = (const float*)d_in[14];
    const float* lng   = (const float*)d_in[15];
    const float* lnb   = (const float*)d_in[16];

    int NQ_ = in_sizes[0] / DIMN;
    int NK_ = in_sizes[1] / DIMN;
    int E_  = in_sizes[3];

    char* p = (char*)d_ws;
    __bf16* wsplit = (__bf16*)p;
    size_t off = (size_t)4 * 32768 * sizeof(__bf16);
    float*  Qp = (float*)(p + off);  off += (size_t)NQ_ * DIMN * 4;
    __bf16* KV = (__bf16*)(p + off); off += (size_t)NK_ * 256 * 2;
    int* counts = (int*)(p + off); off += (((size_t)NQ_ * 4) + 127) / 128 * 128;
    int* offs   = (int*)(p + off); off += (((size_t)NQ_ * 4) + 127) / 128 * 128;
    int* bsum   = (int*)(p + off); off += 1024 * 4;
    int* rank   = (int*)(p + off); off += (size_t)E_ * 4;
    int* skey   = (int*)(p + off); off += (size_t)E_ * 4;
    float* msg  = Qp;  // aliasing is safe: wave for query q reads only Qp row q

    hipMemsetAsync(counts, 0, (size_t)NQ_ * 4, stream);

    int ge = (E_ + 255) / 256;
    int gm = (NQ_ + 63) / 64;
    int nb = (NQ_ + 255) / 256;

    k_prep<<<256 + ge, 256, 0, stream>>>(Wq, Wk, Wv, Wp, wsplit, qidx, counts, rank, E_);

    int ntq = (NQ_ + 31) >> 5;
    int ntk = (NK_ + 31) >> 5;
    int total = ntq + 2 * ntk;
    int chunk = 5;
    int gproj = (total + chunk - 1) / chunk;
    if (gproj < nb) gproj = nb;   // scan1 piggyback needs nb blocks
    k_proj3<<<gproj, 256, 0, stream>>>(query, keys, values, wsplit, bq, bk, bv,
                                       Qp, KV, NQ_, NK_, counts, offs, bsum, nb, chunk);

    k_scan2<<<1, 1024, 0, stream>>>(bsum, nb);

    k_scatter<<<ge, 256, 0, stream>>>(qidx, kidx, offs, bsum, rank, skey, E_);

    k_attn<<<(NQ_ + 3) / 4, 256, 0, stream>>>(Qp, KV, offs, bsum, skey, a, pw, msg, NQ_, E_);

    k_final<<<gm, 256, 0, stream>>>(msg, wsplit + 3 * 32768, wsplit + 3 * 32768 + 16384,
                                    bp, query, lng, lnb, (float*)d_out, NQ_);
}

// Round 7
// 361.899 us; speedup vs baseline: 2.3056x; 1.0048x over previous
//
#include <hip/hip_runtime.h>
#include <hip/hip_bf16.h>

#define DIMN 128
#define LN_EPS 1e-5f
#define WPAD 136   // padded row length in bf16 (272 B = 17*16, keeps b128 aligned, ~2-way banks)

typedef __bf16 bf16x8 __attribute__((ext_vector_type(8)));
typedef float f32x4 __attribute__((ext_vector_type(4)));

__device__ __forceinline__ float bf_even(uint32_t u) {  // element at even dim (low 16 bits)
    union { uint32_t u; float f; } c; c.u = u << 16; return c.f;
}
__device__ __forceinline__ float bf_odd(uint32_t u) {   // element at odd dim (high 16 bits)
    union { uint32_t u; float f; } c; c.u = u & 0xffff0000u; return c.f;
}

// ---------------- K1: W split (blocks 0..255) + hist/rank (rest) ----------------
__global__ __launch_bounds__(256) void k_prep(
        const float* __restrict__ Wq, const float* __restrict__ Wk,
        const float* __restrict__ Wv, const float* __restrict__ Wp,
        __bf16* __restrict__ wsplit, const int* __restrict__ qidx,
        int* __restrict__ counts, int* __restrict__ rank, int E) {
    int bi = blockIdx.x;
    if (bi < 256) {
        int w = bi >> 6;
        const float* W = (w == 0) ? Wq : (w == 1) ? Wk : (w == 2) ? Wv : Wp;
        __bf16* hi = wsplit + (size_t)w * 32768;
        __bf16* lo = hi + 16384;
        int i = (bi & 63) * 256 + threadIdx.x;
        float x = W[i];
        __bf16 h = (__bf16)x;
        hi[i] = h;
        lo[i] = (__bf16)(x - (float)h);
    } else {
        int i = (bi - 256) * 256 + threadIdx.x;
        if (i < E) rank[i] = atomicAdd(&counts[qidx[i]], 1);
    }
}

// ---------------- K2: LDS-W projections (+ scan1 in low blocks) ----------------
__global__ __launch_bounds__(256, 2) void k_proj3(
        const float* __restrict__ query, const float* __restrict__ keys,
        const float* __restrict__ values, const __bf16* __restrict__ wsplit,
        const float* __restrict__ bq, const float* __restrict__ bk,
        const float* __restrict__ bv, float* __restrict__ Qp,
        __bf16* __restrict__ KV, int NQ_, int NK_,
        const int* __restrict__ counts, int* __restrict__ offs,
        int* __restrict__ bsum, int nb, int chunk) {
    __shared__ int s[256];
    __shared__ __align__(16) __bf16 WH[128 * WPAD];
    __shared__ __align__(16) __bf16 WL[128 * WPAD];

    // ---- scan1 piggyback (counts ready: k_prep ran before) ----
    if ((int)blockIdx.x < nb) {
        int t = threadIdx.x;
        int i = blockIdx.x * 256 + t;
        int v = (i < NQ_) ? counts[i] : 0;
        s[t] = v;
        __syncthreads();
        for (int o = 1; o < 256; o <<= 1) {
            int x = (t >= o) ? s[t - o] : 0;
            __syncthreads();
            s[t] += x;
            __syncthreads();
        }
        if (i < NQ_) offs[i] = s[t] - v;
        if (t == 255) bsum[blockIdx.x] = s[t];
    }

    int lane = threadIdx.x & 63;
    int wid  = threadIdx.x >> 6;
    int r = lane & 15, g = lane >> 4;
    int rowoff = (wid >> 1) * 16;   // 0 or 16 within the 32-row tile
    int chalf  = wid & 1;           // column half: cols [chalf*64, chalf*64+64)

    int ntq = (NQ_ + 31) >> 5;
    int ntk = (NK_ + 31) >> 5;
    int total = ntq + 2 * ntk;

    int t0 = blockIdx.x * chunk;
    int t1 = t0 + chunk; if (t1 > total) t1 = total;
    int staged = -1;
    float bias_n[4];

    for (int t = t0; t < t1; ++t) {
        int m, tt;
        if (t < ntq)            { m = 0; tt = t; }
        else if (t < ntq + ntk) { m = 1; tt = t - ntq; }
        else                    { m = 2; tt = t - ntq - ntk; }

        if (m != staged) {
            if (staged != -1) __syncthreads();   // drain readers of old W
            const uint4* srcH = (const uint4*)(wsplit + (size_t)m * 32768);
            const uint4* srcL = (const uint4*)(wsplit + (size_t)m * 32768 + 16384);
#pragma unroll
            for (int it = 0; it < 8; ++it) {
                int cid = threadIdx.x + it * 256;     // 2048 16B-chunks per plane
                int n = cid >> 4, c16 = cid & 15;
                *(uint4*)((char*)WH + n * (WPAD * 2) + c16 * 16) = srcH[cid];
                *(uint4*)((char*)WL + n * (WPAD * 2) + c16 * 16) = srcL[cid];
            }
            __syncthreads();
            staged = m;
            const float* bias = (m == 0) ? bq : (m == 1) ? bk : bv;
#pragma unroll
            for (int c = 0; c < 4; ++c) bias_n[c] = bias[(chalf * 4 + c) * 16 + r];
        }

        const float* X = (m == 0) ? query : (m == 1) ? keys : values;
        int M = (m == 0) ? NQ_ : NK_;
        int rb = tt * 32 + rowoff;
        int arow = rb + r; if (arow >= M) arow = M - 1;
        const float* xrow = X + (size_t)arow * DIMN;

        bf16x8 Ah[4], Al[4];
#pragma unroll
        for (int ks = 0; ks < 4; ++ks) {
            const float* px = xrow + ks * 32 + g * 8;
            f32x4 v0 = *(const f32x4*)(px);
            f32x4 v1 = *(const f32x4*)(px + 4);
#pragma unroll
            for (int i = 0; i < 4; ++i) {
                __bf16 h0 = (__bf16)v0[i];
                __bf16 h1 = (__bf16)v1[i];
                Ah[ks][i]     = h0;
                Ah[ks][i + 4] = h1;
                if (m == 0) {
                    Al[ks][i]     = (__bf16)(v0[i] - (float)h0);
                    Al[ks][i + 4] = (__bf16)(v1[i] - (float)h1);
                }
            }
        }

        f32x4 acc[4];
#pragma unroll
        for (int c = 0; c < 4; ++c) {
            acc[c] = (f32x4){0.f, 0.f, 0.f, 0.f};
            int n = (chalf * 4 + c) * 16 + r;
#pragma unroll
            for (int ks = 0; ks < 4; ++ks) {
                bf16x8 Bh = *(const bf16x8*)(WH + n * WPAD + ks * 32 + g * 8);
                acc[c] = __builtin_amdgcn_mfma_f32_16x16x32_bf16(Ah[ks], Bh, acc[c], 0, 0, 0);
                if (m == 0) {
                    bf16x8 Bl = *(const bf16x8*)(WL + n * WPAD + ks * 32 + g * 8);
                    acc[c] = __builtin_amdgcn_mfma_f32_16x16x32_bf16(Ah[ks], Bl, acc[c], 0, 0, 0);
                    acc[c] = __builtin_amdgcn_mfma_f32_16x16x32_bf16(Al[ks], Bh, acc[c], 0, 0, 0);
                }
            }
        }

        if (m == 0) {
#pragma unroll
            for (int c = 0; c < 4; ++c) {
                int n = (chalf * 4 + c) * 16 + r;
#pragma unroll
                for (int i = 0; i < 4; ++i) {
                    int row = rb + g * 4 + i;
                    if (row < M) Qp[(size_t)row * DIMN + n] = acc[c][i] + bias_n[c];
                }
            }
        } else {
            int vofs = (m == 2) ? 128 : 0;
#pragma unroll
            for (int c = 0; c < 4; ++c) {
                int n = (chalf * 4 + c) * 16 + r;
#pragma unroll
                for (int i = 0; i < 4; ++i) {
                    int row = rb + g * 4 + i;
                    if (row < M) KV[(size_t)row * 256 + vofs + n] = (__bf16)(acc[c][i] + bias_n[c]);
                }
            }
        }
    }
}

__global__ __launch_bounds__(1024) void k_scan2(int* __restrict__ bsum, int nb) {
    __shared__ int s[1024];
    int t = threadIdx.x;
    int v = (t < nb) ? bsum[t] : 0;
    s[t] = v;
    __syncthreads();
    for (int o = 1; o < 1024; o <<= 1) {
        int x = (t >= o) ? s[t - o] : 0;
        __syncthreads();
        s[t] += x;
        __syncthreads();
    }
    if (t < nb) bsum[t] = s[t];  // inclusive block-sum scan
}

// final offset of query i = offs[i] + (i>=256 ? bsum[i/256-1] : 0)
__global__ void k_scatter(const int* __restrict__ qidx, const int* __restrict__ kidx,
                          const int* __restrict__ offs, const int* __restrict__ bsum,
                          const int* __restrict__ rank, int* __restrict__ skey, int E) {
    int i = blockIdx.x * 256 + threadIdx.x;
    if (i < E) {
        int q = qidx[i];
        int base = offs[q] + ((q >= 256) ? bsum[(q >> 8) - 1] : 0);
        skey[base + rank[i]] = kidx[i];
    }
}

// ---------------- per-query softmax aggregation ----------------
// 4 edges per wave (16 lanes / edge, 8 dims / lane, dwordx4 K and V loads).
// Per-edge overhead (skey, addr, loads, reduce, exp, den) drops ~4x vs the
// 1-edge/wave form. Head = 16 dims = 2 lanes -> single xor1 swizzle reduce.
// Cross-group combine once per query: xor16 swizzle + xor32 shfl on 9 regs.
__device__ __forceinline__ float score8(uint4 ku, const f32x4& qa, const f32x4& qb,
                                        const f32x4& aa, const f32x4& ab, float pw) {
    float e, x;
    x = qa[0] + bf_even(ku.x); x = x >= 0.f ? x : pw * x; e  = aa[0] * x;
    x = qa[1] + bf_odd (ku.x); x = x >= 0.f ? x : pw * x; e += aa[1] * x;
    x = qa[2] + bf_even(ku.y); x = x >= 0.f ? x : pw * x; e += aa[2] * x;
    x = qa[3] + bf_odd (ku.y); x = x >= 0.f ? x : pw * x; e += aa[3] * x;
    x = qb[0] + bf_even(ku.z); x = x >= 0.f ? x : pw * x; e += ab[0] * x;
    x = qb[1] + bf_odd (ku.z); x = x >= 0.f ? x : pw * x; e += ab[1] * x;
    x = qb[2] + bf_even(ku.w); x = x >= 0.f ? x : pw * x; e += ab[2] * x;
    x = qb[3] + bf_odd (ku.w); x = x >= 0.f ? x : pw * x; e += ab[3] * x;
    return e;
}

__device__ __forceinline__ void acc8(uint4 vu, float w, f32x4& c0, f32x4& c1) {
    c0[0] += w * bf_even(vu.x); c0[1] += w * bf_odd(vu.x);
    c0[2] += w * bf_even(vu.y); c0[3] += w * bf_odd(vu.y);
    c1[0] += w * bf_even(vu.z); c1[1] += w * bf_odd(vu.z);
    c1[2] += w * bf_even(vu.w); c1[3] += w * bf_odd(vu.w);
}

__device__ __forceinline__ float red1(float v) {   // += partner lane (xor 1)
    return v + __int_as_float(__builtin_amdgcn_ds_swizzle(__float_as_int(v), 0x041F));
}
__device__ __forceinline__ float redg(float v) {   // += across the 4 edge groups
    v += __int_as_float(__builtin_amdgcn_ds_swizzle(__float_as_int(v), 0x401F)); // xor16
    v += __shfl_xor(v, 32, 64);                                                  // xor32
    return v;
}

__global__ __launch_bounds__(256) void k_attn(
        const float* __restrict__ Qp, const __bf16* __restrict__ KV,
        const int* __restrict__ offs, const int* __restrict__ bsum,
        const int* __restrict__ skey, const float* __restrict__ a,
        const float* __restrict__ prelu_w, float* __restrict__ msg,
        int NQ_, int E_) {
    int lane = threadIdx.x & 63;
    int q = blockIdx.x * 4 + (threadIdx.x >> 6);
    if (q >= NQ_) return;
    int l16 = lane & 15;
    int grp = lane >> 4;
    int d0 = l16 * 8;

    f32x4 aa = *(const f32x4*)(a + d0);
    f32x4 ab = *(const f32x4*)(a + d0 + 4);
    f32x4 qa = *(const f32x4*)(Qp + (size_t)q * DIMN + d0);
    f32x4 qb = *(const f32x4*)(Qp + (size_t)q * DIMN + d0 + 4);
    float pw = prelu_w[0];

    int beg = offs[q] + ((q >= 256) ? bsum[(q >> 8) - 1] : 0);
    int qn = q + 1;
    int end = (qn == NQ_) ? E_ : offs[qn] + ((qn >= 256) ? bsum[(qn >> 8) - 1] : 0);

    float den = 0.f;
    f32x4 c0 = {0.f, 0.f, 0.f, 0.f}, c1 = {0.f, 0.f, 0.f, 0.f};
    int j = beg;
    for (; j + 4 < end; j += 8) {          // group A fully active, group B masked
        int kA = skey[j + grp];
        int jB = j + 4 + grp;
        int kB = skey[jB < end ? jB : end - 1];
        const uint4* rA = (const uint4*)(KV + ((size_t)kA << 8));
        const uint4* rB = (const uint4*)(KV + ((size_t)kB << 8));
        uint4 kuA = rA[l16], vuA = rA[16 + l16];
        uint4 kuB = rB[l16], vuB = rB[16 + l16];
        float eA = red1(score8(kuA, qa, qb, aa, ab, pw));
        float eB = red1(score8(kuB, qa, qb, aa, ab, pw));
        float wA = __expf(eA);
        float wB = (jB < end) ? __expf(eB) : 0.f;
        den += wA + wB;
        acc8(vuA, wA, c0, c1);
        acc8(vuB, wB, c0, c1);
    }
    if (j < end) {                          // masked remainder group
        int jj = j + grp;
        int k = skey[jj < end ? jj : end - 1];
        const uint4* r_ = (const uint4*)(KV + ((size_t)k << 8));
        uint4 ku = r_[l16], vu = r_[16 + l16];
        float e = red1(score8(ku, qa, qb, aa, ab, pw));
        float w = (jj < end) ? __expf(e) : 0.f;
        den += w;
        acc8(vu, w, c0, c1);
    }

#pragma unroll
    for (int i = 0; i < 4; ++i) { c0[i] = redg(c0[i]); c1[i] = redg(c1[i]); }
    den = redg(den);
    float inv = den > 0.f ? 1.f / den : 0.f;
    if (grp == 0) {
        f32x4 o0, o1;
#pragma unroll
        for (int i = 0; i < 4; ++i) { o0[i] = c0[i] * inv; o1[i] = c1[i] * inv; }
        *(f32x4*)(msg + (size_t)q * DIMN + d0)     = o0;   // msg aliases Qp (row q only)
        *(f32x4*)(msg + (size_t)q * DIMN + d0 + 4) = o1;
    }
}

// ---------------- final: x = query + msg@Wp^T + bp; LayerNorm ----------------
__global__ __launch_bounds__(256, 2) void k_final(
        const float* __restrict__ msg, const __bf16* __restrict__ wh,
        const __bf16* __restrict__ wl, const float* __restrict__ bp,
        const float* __restrict__ query, const float* __restrict__ lng,
        const float* __restrict__ lnb, float* __restrict__ out, int M) {
    __shared__ __align__(16) __bf16 WH[128 * WPAD];
    __shared__ __align__(16) __bf16 WL[128 * WPAD];
    {
        const uint4* srcH = (const uint4*)wh;
        const uint4* srcL = (const uint4*)wl;
#pragma unroll
        for (int it = 0; it < 8; ++it) {
            int cid = threadIdx.x + it * 256;
            int n = cid >> 4, c16 = cid & 15;
            *(uint4*)((char*)WH + n * (WPAD * 2) + c16 * 16) = srcH[cid];
            *(uint4*)((char*)WL + n * (WPAD * 2) + c16 * 16) = srcL[cid];
        }
    }
    __syncthreads();

    int lane = threadIdx.x & 63;
    int wid  = threadIdx.x >> 6;
    int r = lane & 15, g = lane >> 4;
    int rb = blockIdx.x * 64 + wid * 16;

    int arow = rb + r; if (arow >= M) arow = M - 1;
    const float* xrow = msg + (size_t)arow * DIMN;
    bf16x8 Ah[4], Al[4];
#pragma unroll
    for (int ks = 0; ks < 4; ++ks) {
        const float* px = xrow + ks * 32 + g * 8;
        f32x4 v0 = *(const f32x4*)(px);
        f32x4 v1 = *(const f32x4*)(px + 4);
#pragma unroll
        for (int i = 0; i < 4; ++i) {
            __bf16 h0 = (__bf16)v0[i];
            __bf16 h1 = (__bf16)v1[i];
            Ah[ks][i]     = h0;
            Ah[ks][i + 4] = h1;
            Al[ks][i]     = (__bf16)(v0[i] - (float)h0);
            Al[ks][i + 4] = (__bf16)(v1[i] - (float)h1);
        }
    }
    float xv[8][4];
#pragma unroll
    for (int ct = 0; ct < 8; ++ct) {
        f32x4 acc = {0.f, 0.f, 0.f, 0.f};
        int n = ct * 16 + r;
#pragma unroll
        for (int ks = 0; ks < 4; ++ks) {
            bf16x8 Bh = *(const bf16x8*)(WH + n * WPAD + ks * 32 + g * 8);
            bf16x8 Bl = *(const bf16x8*)(WL + n * WPAD + ks * 32 + g * 8);
            acc = __builtin_amdgcn_mfma_f32_16x16x32_bf16(Ah[ks], Bh, acc, 0, 0, 0);
            acc = __builtin_amdgcn_mfma_f32_16x16x32_bf16(Ah[ks], Bl, acc, 0, 0, 0);
            acc = __builtin_amdgcn_mfma_f32_16x16x32_bf16(Al[ks], Bh, acc, 0, 0, 0);
        }
        float bn = bp[n];
#pragma unroll
        for (int i = 0; i < 4; ++i) {
            int row = rb + g * 4 + i;
            int rc = row < M ? row : M - 1;
            xv[ct][i] = acc[i] + bn + query[(size_t)rc * DIMN + n];
        }
    }
#pragma unroll
    for (int i = 0; i < 4; ++i) {
        float s = 0.f, ss = 0.f;
#pragma unroll
        for (int ct = 0; ct < 8; ++ct) { s += xv[ct][i]; ss += xv[ct][i] * xv[ct][i]; }
        s += __shfl_xor(s, 1, 64);  ss += __shfl_xor(ss, 1, 64);
        s += __shfl_xor(s, 2, 64);  ss += __shfl_xor(ss, 2, 64);
        s += __shfl_xor(s, 4, 64);  ss += __shfl_xor(ss, 4, 64);
        s += __shfl_xor(s, 8, 64);  ss += __shfl_xor(ss, 8, 64);
        float mean = s * (1.f / DIMN);
        float var  = ss * (1.f / DIMN) - mean * mean;
        float rstd = rsqrtf(var + LN_EPS);
        int row = rb + g * 4 + i;
#pragma unroll
        for (int ct = 0; ct < 8; ++ct) {
            int n = ct * 16 + r;
            if (row < M)
                out[(size_t)row * DIMN + n] = (xv[ct][i] - mean) * rstd * lng[n] + lnb[n];
        }
    }
}

extern "C" void kernel_launch(void* const* d_in, const int* in_sizes, int n_in,
                              void* d_out, int out_size, void* d_ws, size_t ws_size,
                              hipStream_t stream) {
    const float* query = (const float*)d_in[0];
    const float* keys  = (const float*)d_in[1];
    const float* values= (const float*)d_in[2];
    const int*   qidx  = (const int*)d_in[3];
    const int*   kidx  = (const int*)d_in[4];
    const float* Wq    = (const float*)d_in[5];
    const float* bq    = (const float*)d_in[6];
    const float* Wk    = (const float*)d_in[7];
    const float* bk    = (const float*)d_in[8];
    const float* Wv    = (const float*)d_in[9];
    const float* bv    = (const float*)d_in[10];
    const float* Wp    = (const float*)d_in[11];
    const float* bp    = (const float*)d_in[12];
    const float* a     = (const float*)d_in[13];
    const float* pw    = (const float*)d_in[14];
    const float* lng   = (const float*)d_in[15];
    const float* lnb   = (const float*)d_in[16];

    int NQ_ = in_sizes[0] / DIMN;
    int NK_ = in_sizes[1] / DIMN;
    int E_  = in_sizes[3];

    char* p = (char*)d_ws;
    __bf16* wsplit = (__bf16*)p;
    size_t off = (size_t)4 * 32768 * sizeof(__bf16);
    float*  Qp = (float*)(p + off);  off += (size_t)NQ_ * DIMN * 4;
    __bf16* KV = (__bf16*)(p + off); off += (size_t)NK_ * 256 * 2;
    int* counts = (int*)(p + off); off += (((size_t)NQ_ * 4) + 127) / 128 * 128;
    int* offs   = (int*)(p + off); off += (((size_t)NQ_ * 4) + 127) / 128 * 128;
    int* bsum   = (int*)(p + off); off += 1024 * 4;
    int* rank   = (int*)(p + off); off += (size_t)E_ * 4;
    int* skey   = (int*)(p + off); off += (size_t)E_ * 4;
    float* msg  = Qp;  // aliasing is safe: wave for query q reads only Qp row q

    hipMemsetAsync(counts, 0, (size_t)NQ_ * 4, stream);

    int ge = (E_ + 255) / 256;
    int gm = (NQ_ + 63) / 64;
    int nb = (NQ_ + 255) / 256;

    k_prep<<<256 + ge, 256, 0, stream>>>(Wq, Wk, Wv, Wp, wsplit, qidx, counts, rank, E_);

    int ntq = (NQ_ + 31) >> 5;
    int ntk = (NK_ + 31) >> 5;
    int total = ntq + 2 * ntk;
    int chunk = 5;
    int gproj = (total + chunk - 1) / chunk;
    if (gproj < nb) gproj = nb;   // scan1 piggyback needs nb blocks
    k_proj3<<<gproj, 256, 0, stream>>>(query, keys, values, wsplit, bq, bk, bv,
                                       Qp, KV, NQ_, NK_, counts, offs, bsum, nb, chunk);

    k_scan2<<<1, 1024, 0, stream>>>(bsum, nb);

    k_scatter<<<ge, 256, 0, stream>>>(qidx, kidx, offs, bsum, rank, skey, E_);

    k_attn<<<(NQ_ + 3) / 4, 256, 0, stream>>>(Qp, KV, offs, bsum, skey, a, pw, msg, NQ_, E_);

    k_final<<<gm, 256, 0, stream>>>(msg, wsplit + 3 * 32768, wsplit + 3 * 32768 + 16384,
                                    bp, query, lng, lnb, (float*)d_out, NQ_);
}